// Round 1
// baseline (1906.437 us; speedup 1.0000x reference)
//
#include <hip/hip_runtime.h>

#define NN 100000
#define EE 1000000

// ---------------------------------------------------------------------------
// K1: layer-1 scatter.  16 threads per edge; each thread gathers a float4 of
// x[src] and atomically adds into agg1[dst].  Lane q==0 bumps the in-degree.
// ---------------------------------------------------------------------------
__global__ __launch_bounds__(256) void k_scatter1(
    const float* __restrict__ x, const int* __restrict__ ei,
    float* __restrict__ agg1, float* __restrict__ deg)
{
    long tid = (long)blockIdx.x * blockDim.x + threadIdx.x;
    if (tid >= (long)EE * 16) return;
    int e = (int)(tid >> 4);
    int q = (int)(tid & 15);
    int src = ei[e];
    int dst = ei[EE + e];
    const float4 v = *reinterpret_cast<const float4*>(x + (size_t)src * 64 + q * 4);
    float* a = agg1 + (size_t)dst * 64 + q * 4;
    atomicAdd(a + 0, v.x);
    atomicAdd(a + 1, v.y);
    atomicAdd(a + 2, v.z);
    atomicAdd(a + 3, v.w);
    if (q == 0) atomicAdd(deg + dst, 1.0f);
}

// ---------------------------------------------------------------------------
// K2: layer-1 dense.  Wave-per-node: h = relu(agg1/deg @ W1l + x @ W1r + b1).
// Also pre-computes hW2l = h @ W2l (mean is linear -> scatter 40 floats/edge
// in layer 2 instead of 64).  Weights staged in LDS, activation rows
// broadcast via __shfl.
// ---------------------------------------------------------------------------
__global__ __launch_bounds__(256) void k_layer1(
    const float* __restrict__ x,   const float* __restrict__ W1l,
    const float* __restrict__ W1r, const float* __restrict__ b1,
    const float* __restrict__ W2l,
    const float* __restrict__ agg1, const float* __restrict__ deg,
    float* __restrict__ h, float* __restrict__ hW2l)
{
    __shared__ float sW1l[64 * 64];
    __shared__ float sW1r[64 * 64];
    __shared__ float sW2l[64 * 40];
    __shared__ float sB1[64];
    for (int i = threadIdx.x; i < 64 * 64; i += 256) { sW1l[i] = W1l[i]; sW1r[i] = W1r[i]; }
    for (int i = threadIdx.x; i < 64 * 40; i += 256) sW2l[i] = W2l[i];
    if (threadIdx.x < 64) sB1[threadIdx.x] = b1[threadIdx.x];
    __syncthreads();

    const int w    = threadIdx.x >> 6;
    const int lane = threadIdx.x & 63;
    const int node = blockIdx.x * 4 + w;          // grid = NN/4 exactly

    const float d    = fmaxf(deg[node], 1.0f);
    const float aval = agg1[(size_t)node * 64 + lane] / d;   // mean-aggregated row elem
    const float xval = x[(size_t)node * 64 + lane];

    float acc = sB1[lane];
    #pragma unroll
    for (int k = 0; k < 64; ++k) {
        acc += __shfl(aval, k) * sW1l[k * 64 + lane]
             + __shfl(xval, k) * sW1r[k * 64 + lane];
    }
    const float hv = fmaxf(acc, 0.0f);
    h[(size_t)node * 64 + lane] = hv;

    const int li = lane < 40 ? lane : 0;          // keep LDS index in-bounds
    float acc2 = 0.0f;
    #pragma unroll
    for (int k = 0; k < 64; ++k)
        acc2 += __shfl(hv, k) * sW2l[k * 40 + li];
    if (lane < 40) hW2l[(size_t)node * 40 + lane] = acc2;
}

// ---------------------------------------------------------------------------
// K3: layer-2 scatter.  10 threads per edge; float4 gather of hW2l[src],
// atomic adds into agg2[dst] (40 floats per row, rows 160B-aligned).
// ---------------------------------------------------------------------------
__global__ __launch_bounds__(256) void k_scatter2(
    const float* __restrict__ hW2l, const int* __restrict__ ei,
    float* __restrict__ agg2)
{
    long tid = (long)blockIdx.x * blockDim.x + threadIdx.x;
    if (tid >= (long)EE * 10) return;
    int e = (int)(tid / 10);
    int q = (int)(tid % 10);
    int src = ei[e];
    int dst = ei[EE + e];
    const float4 v = *reinterpret_cast<const float4*>(hW2l + (size_t)src * 40 + q * 4);
    float* a = agg2 + (size_t)dst * 40 + q * 4;
    atomicAdd(a + 0, v.x);
    atomicAdd(a + 1, v.y);
    atomicAdd(a + 2, v.z);
    atomicAdd(a + 3, v.w);
}

// ---------------------------------------------------------------------------
// K4: layer-2 combine.  out = agg2/deg + h @ W2r + b2.  Wave-per-node again.
// ---------------------------------------------------------------------------
__global__ __launch_bounds__(256) void k_layer2(
    const float* __restrict__ h,  const float* __restrict__ W2r,
    const float* __restrict__ b2, const float* __restrict__ agg2,
    const float* __restrict__ deg, float* __restrict__ out)
{
    __shared__ float sW2r[64 * 40];
    __shared__ float sB2[40];
    for (int i = threadIdx.x; i < 64 * 40; i += 256) sW2r[i] = W2r[i];
    if (threadIdx.x < 40) sB2[threadIdx.x] = b2[threadIdx.x];
    __syncthreads();

    const int w    = threadIdx.x >> 6;
    const int lane = threadIdx.x & 63;
    const int node = blockIdx.x * 4 + w;

    const float hv = h[(size_t)node * 64 + lane];
    const int li = lane < 40 ? lane : 0;
    float acc = 0.0f;
    #pragma unroll
    for (int k = 0; k < 64; ++k)
        acc += __shfl(hv, k) * sW2r[k * 40 + li];

    if (lane < 40) {
        const float d = fmaxf(deg[node], 1.0f);
        out[(size_t)node * 40 + lane] =
            agg2[(size_t)node * 40 + lane] / d + acc + sB2[lane];
    }
}

// ---------------------------------------------------------------------------
// Workspace layout (floats):
//   [0, N)            deg
//   [N, 65N)          agg1   (N x 64)
//   [65N, 105N)       agg2   (N x 40)
//   [105N, 169N)      h      (N x 64)
//   [169N, 209N)      hW2l   (N x 40)
// Total 209N * 4 B = 83.6 MB.  First 105N floats zeroed every call.
// ---------------------------------------------------------------------------
extern "C" void kernel_launch(void* const* d_in, const int* in_sizes, int n_in,
                              void* d_out, int out_size, void* d_ws, size_t ws_size,
                              hipStream_t stream) {
    const float* x   = (const float*)d_in[0];
    const int*   ei  = (const int*)  d_in[1];
    const float* W1l = (const float*)d_in[2];
    const float* W1r = (const float*)d_in[3];
    const float* b1  = (const float*)d_in[4];
    const float* W2l = (const float*)d_in[5];
    const float* W2r = (const float*)d_in[6];
    const float* b2  = (const float*)d_in[7];
    float* out = (float*)d_out;

    float* ws   = (float*)d_ws;
    float* deg  = ws;
    float* agg1 = ws + NN;
    float* agg2 = agg1 + (size_t)NN * 64;
    float* h    = agg2 + (size_t)NN * 40;
    float* hW2l = h    + (size_t)NN * 64;

    hipMemsetAsync(d_ws, 0, sizeof(float) * (size_t)NN * 105, stream);

    {   // layer-1 scatter: E*16 threads
        long t = (long)EE * 16;
        k_scatter1<<<(int)((t + 255) / 256), 256, 0, stream>>>(x, ei, agg1, deg);
    }
    k_layer1<<<NN / 4, 256, 0, stream>>>(x, W1l, W1r, b1, W2l, agg1, deg, h, hW2l);
    {   // layer-2 scatter: E*10 threads
        long t = (long)EE * 10;
        k_scatter2<<<(int)((t + 255) / 256), 256, 0, stream>>>(hW2l, ei, agg2);
    }
    k_layer2<<<NN / 4, 256, 0, stream>>>(h, W2r, b2, agg2, deg, out);
}

// Round 2
// 773.973 us; speedup vs baseline: 2.4632x; 2.4632x over previous
//
#include <hip/hip_runtime.h>

#define NN 100000
#define EE 1000000

// ---------------------------------------------------------------------------
// K1: histogram of dst -> deg_i  (1M int atomics on 400KB, L2-resident)
// ---------------------------------------------------------------------------
__global__ __launch_bounds__(256) void k_hist(
    const int* __restrict__ ei, int* __restrict__ deg_i)
{
    int e = blockIdx.x * blockDim.x + threadIdx.x;
    if (e >= EE) return;
    atomicAdd(deg_i + ei[EE + e], 1);
}

// ---------------------------------------------------------------------------
// K2: exclusive prefix sum of deg_i -> rowptr[NN+1].  Single 1024-thread
// block; each thread serially sums a 98-element chunk, Hillis-Steele scan of
// the 1024 partials in LDS, then serial exclusive writeback.
// ---------------------------------------------------------------------------
#define SCAN_T 1024
#define SCAN_CH 98   // ceil(NN/1024)
__global__ __launch_bounds__(SCAN_T) void k_scan(
    const int* __restrict__ deg_i, int* __restrict__ rowptr)
{
    __shared__ int part[SCAN_T];
    const int t = threadIdx.x;
    const int base = t * SCAN_CH;
    int s = 0;
    for (int i = 0; i < SCAN_CH; ++i) {
        int idx = base + i;
        if (idx < NN) s += deg_i[idx];
    }
    part[t] = s;
    __syncthreads();
    for (int off = 1; off < SCAN_T; off <<= 1) {
        int v = (t >= off) ? part[t - off] : 0;
        __syncthreads();
        part[t] += v;
        __syncthreads();
    }
    int run = (t == 0) ? 0 : part[t - 1];
    for (int i = 0; i < SCAN_CH; ++i) {
        int idx = base + i;
        if (idx < NN) { rowptr[idx] = run; run += deg_i[idx]; }
    }
    if (t == SCAN_T - 1) rowptr[NN] = run;   // == EE
}

// ---------------------------------------------------------------------------
// K3: bucket fill: srcs[rowptr[dst] + cursor[dst]++] = src
// ---------------------------------------------------------------------------
__global__ __launch_bounds__(256) void k_fill(
    const int* __restrict__ ei, const int* __restrict__ rowptr,
    int* __restrict__ cursor, int* __restrict__ srcs)
{
    int e = blockIdx.x * blockDim.x + threadIdx.x;
    if (e >= EE) return;
    int dst = ei[EE + e];
    int pos = rowptr[dst] + atomicAdd(cursor + dst, 1);
    srcs[pos] = ei[e];
}

// ---------------------------------------------------------------------------
// K4: fused layer-1.  Wave-per-node: gather+mean of x[neighbors] in regs,
// then h = relu(mean @ W1l + x @ W1r + b1), and hW2l = h @ W2l.
// ---------------------------------------------------------------------------
__global__ __launch_bounds__(256) void k_l1(
    const float* __restrict__ x,   const float* __restrict__ W1l,
    const float* __restrict__ W1r, const float* __restrict__ b1,
    const float* __restrict__ W2l,
    const int* __restrict__ rowptr, const int* __restrict__ srcs,
    float* __restrict__ h, float* __restrict__ hW2l)
{
    __shared__ float sW1l[64 * 64];
    __shared__ float sW1r[64 * 64];
    __shared__ float sW2l[64 * 40];
    __shared__ float sB1[64];
    for (int i = threadIdx.x; i < 64 * 64; i += 256) { sW1l[i] = W1l[i]; sW1r[i] = W1r[i]; }
    for (int i = threadIdx.x; i < 64 * 40; i += 256) sW2l[i] = W2l[i];
    if (threadIdx.x < 64) sB1[threadIdx.x] = b1[threadIdx.x];
    __syncthreads();

    const int w    = threadIdx.x >> 6;
    const int lane = threadIdx.x & 63;
    const int node = blockIdx.x * 4 + w;          // grid = NN/4 exactly

    const int beg = rowptr[node];
    const int end = rowptr[node + 1];
    const int nb  = end - beg;

    // Gather-sum neighbor rows (coalesced 256B per edge), 4-way unrolled.
    float a0 = 0.f, a1 = 0.f;
    for (int j0 = 0; j0 < nb; j0 += 64) {
        const int cnt = min(nb - j0, 64);
        const int idx = (j0 + lane < nb) ? srcs[beg + j0 + lane] : 0;
        int t = 0;
        for (; t + 3 < cnt; t += 4) {
            int s0 = __shfl(idx, t),     s1 = __shfl(idx, t + 1);
            int s2 = __shfl(idx, t + 2), s3 = __shfl(idx, t + 3);
            float v0 = x[(size_t)s0 * 64 + lane];
            float v1 = x[(size_t)s1 * 64 + lane];
            float v2 = x[(size_t)s2 * 64 + lane];
            float v3 = x[(size_t)s3 * 64 + lane];
            a0 += v0 + v2; a1 += v1 + v3;
        }
        for (; t < cnt; ++t) {
            int s = __shfl(idx, t);
            a0 += x[(size_t)s * 64 + lane];
        }
    }
    const float d    = (float)max(nb, 1);
    const float aval = (a0 + a1) / d;
    const float xval = x[(size_t)node * 64 + lane];

    float acc = sB1[lane];
    #pragma unroll
    for (int k = 0; k < 64; ++k) {
        acc += __shfl(aval, k) * sW1l[k * 64 + lane]
             + __shfl(xval, k) * sW1r[k * 64 + lane];
    }
    const float hv = fmaxf(acc, 0.0f);
    h[(size_t)node * 64 + lane] = hv;

    const int li = lane < 40 ? lane : 0;
    float acc2 = 0.0f;
    #pragma unroll
    for (int k = 0; k < 64; ++k)
        acc2 += __shfl(hv, k) * sW2l[k * 40 + li];
    if (lane < 40) hW2l[(size_t)node * 40 + lane] = acc2;
}

// ---------------------------------------------------------------------------
// K5: fused layer-2.  Wave-per-node: gather+mean of hW2l[neighbors] (40 wide),
// out = mean + h @ W2r + b2.
// ---------------------------------------------------------------------------
__global__ __launch_bounds__(256) void k_l2(
    const float* __restrict__ h,  const float* __restrict__ W2r,
    const float* __restrict__ b2, const float* __restrict__ hW2l,
    const int* __restrict__ rowptr, const int* __restrict__ srcs,
    float* __restrict__ out)
{
    __shared__ float sW2r[64 * 40];
    __shared__ float sB2[40];
    for (int i = threadIdx.x; i < 64 * 40; i += 256) sW2r[i] = W2r[i];
    if (threadIdx.x < 40) sB2[threadIdx.x] = b2[threadIdx.x];
    __syncthreads();

    const int w    = threadIdx.x >> 6;
    const int lane = threadIdx.x & 63;
    const int node = blockIdx.x * 4 + w;
    const int li   = lane < 40 ? lane : 0;

    const int beg = rowptr[node];
    const int end = rowptr[node + 1];
    const int nb  = end - beg;

    float a0 = 0.f, a1 = 0.f;
    for (int j0 = 0; j0 < nb; j0 += 64) {
        const int cnt = min(nb - j0, 64);
        const int idx = (j0 + lane < nb) ? srcs[beg + j0 + lane] : 0;
        int t = 0;
        for (; t + 3 < cnt; t += 4) {
            int s0 = __shfl(idx, t),     s1 = __shfl(idx, t + 1);
            int s2 = __shfl(idx, t + 2), s3 = __shfl(idx, t + 3);
            float v0 = hW2l[(size_t)s0 * 40 + li];
            float v1 = hW2l[(size_t)s1 * 40 + li];
            float v2 = hW2l[(size_t)s2 * 40 + li];
            float v3 = hW2l[(size_t)s3 * 40 + li];
            a0 += v0 + v2; a1 += v1 + v3;
        }
        for (; t < cnt; ++t) {
            int s = __shfl(idx, t);
            a0 += hW2l[(size_t)s * 40 + li];
        }
    }
    const float d = (float)max(nb, 1);
    const float aggv = (a0 + a1) / d;

    const float hv = h[(size_t)node * 64 + lane];
    float acc = 0.0f;
    #pragma unroll
    for (int k = 0; k < 64; ++k)
        acc += __shfl(hv, k) * sW2r[k * 40 + li];

    if (lane < 40)
        out[(size_t)node * 40 + lane] = aggv + acc + sB2[lane];
}

// ---------------------------------------------------------------------------
// Workspace layout (4-byte units):
//   [0, NN)                  deg_i   (int)
//   [NN, 2NN)                cursor  (int)
//   [2NN, 3NN+8)             rowptr  (int, NN+1 used)
//   [3NN+8, 3NN+8+EE)        srcs    (int)
//   then: h (NN*64 f32), hW2l (NN*40 f32).   Total ~46.8 MB.
//   Only deg_i+cursor (800KB) zeroed per call.
// ---------------------------------------------------------------------------
extern "C" void kernel_launch(void* const* d_in, const int* in_sizes, int n_in,
                              void* d_out, int out_size, void* d_ws, size_t ws_size,
                              hipStream_t stream) {
    const float* x   = (const float*)d_in[0];
    const int*   ei  = (const int*)  d_in[1];
    const float* W1l = (const float*)d_in[2];
    const float* W1r = (const float*)d_in[3];
    const float* b1  = (const float*)d_in[4];
    const float* W2l = (const float*)d_in[5];
    const float* W2r = (const float*)d_in[6];
    const float* b2  = (const float*)d_in[7];
    float* out = (float*)d_out;

    int*   wsi    = (int*)d_ws;
    int*   deg_i  = wsi;
    int*   cursor = wsi + NN;
    int*   rowptr = wsi + 2 * NN;
    int*   srcs   = wsi + 3 * NN + 8;
    float* h      = (float*)(wsi + 3 * NN + 8 + EE);
    float* hW2l   = h + (size_t)NN * 64;

    hipMemsetAsync(d_ws, 0, sizeof(int) * (size_t)2 * NN, stream);

    k_hist<<<(EE + 255) / 256, 256, 0, stream>>>(ei, deg_i);
    k_scan<<<1, SCAN_T, 0, stream>>>(deg_i, rowptr);
    k_fill<<<(EE + 255) / 256, 256, 0, stream>>>(ei, rowptr, cursor, srcs);
    k_l1<<<NN / 4, 256, 0, stream>>>(x, W1l, W1r, b1, W2l, rowptr, srcs, h, hW2l);
    k_l2<<<NN / 4, 256, 0, stream>>>(h, W2r, b2, hW2l, rowptr, srcs, out);
}

// Round 3
// 714.638 us; speedup vs baseline: 2.6677x; 1.0830x over previous
//
#include <hip/hip_runtime.h>

#define NN 100000
#define EE 1000000

// ---------------------------------------------------------------------------
// K1: histogram of dst -> deg_i  (1M int atomics on 400KB, L2-resident)
// ---------------------------------------------------------------------------
__global__ __launch_bounds__(256) void k_hist(
    const int* __restrict__ ei, int* __restrict__ deg_i)
{
    int e = blockIdx.x * blockDim.x + threadIdx.x;
    if (e < EE) atomicAdd(deg_i + ei[EE + e], 1);
}

// ---------------------------------------------------------------------------
// K2: exclusive prefix sum of deg_i -> rowptr[NN+1].  Single 1024-thread block.
// ---------------------------------------------------------------------------
#define SCAN_T 1024
#define SCAN_CH 98   // ceil(NN/1024)
__global__ __launch_bounds__(SCAN_T) void k_scan(
    const int* __restrict__ deg_i, int* __restrict__ rowptr)
{
    __shared__ int part[SCAN_T];
    const int t = threadIdx.x;
    const int base = t * SCAN_CH;
    int s = 0;
    for (int i = 0; i < SCAN_CH; ++i) {
        int idx = base + i;
        if (idx < NN) s += deg_i[idx];
    }
    part[t] = s;
    __syncthreads();
    for (int off = 1; off < SCAN_T; off <<= 1) {
        int v = (t >= off) ? part[t - off] : 0;
        __syncthreads();
        part[t] += v;
        __syncthreads();
    }
    int run = (t == 0) ? 0 : part[t - 1];
    for (int i = 0; i < SCAN_CH; ++i) {
        int idx = base + i;
        if (idx < NN) { rowptr[idx] = run; run += deg_i[idx]; }
    }
    if (t == SCAN_T - 1) rowptr[NN] = run;   // == EE
}

// ---------------------------------------------------------------------------
// K3: bucket fill: srcs[rowptr[dst] + cursor[dst]++] = src
// ---------------------------------------------------------------------------
__global__ __launch_bounds__(256) void k_fill(
    const int* __restrict__ ei, const int* __restrict__ rowptr,
    int* __restrict__ cursor, int* __restrict__ srcs)
{
    int e = blockIdx.x * blockDim.x + threadIdx.x;
    if (e >= EE) return;
    int dst = ei[EE + e];
    int pos = rowptr[dst] + atomicAdd(cursor + dst, 1);
    srcs[pos] = ei[e];
}

// ---------------------------------------------------------------------------
// K4: gather-mean over stride-64 rows.  16 lanes per node (float4 each =
// one full 64-float row per group), 4 nodes/wave, 16 nodes/block, no LDS,
// 4-way unrolled -> ~16 outstanding loads per wave at full occupancy.
// aggm[node] = mean_{s in N(node)} rows[s]   (already divided by degree)
// ---------------------------------------------------------------------------
__global__ __launch_bounds__(256, 8) void k_gather1(
    const float* __restrict__ rows, const int* __restrict__ rowptr,
    const int* __restrict__ srcs, float* __restrict__ aggm)
{
    const int lane  = threadIdx.x & 63;
    const int w     = threadIdx.x >> 6;
    const int q     = lane & 15;
    const int gbase = lane & 48;                 // group base lane within wave
    const int node  = blockIdx.x * 16 + w * 4 + (lane >> 4);

    const int beg = rowptr[node];
    const int nb  = rowptr[node + 1] - beg;

    float a0=0.f,a1=0.f,a2=0.f,a3=0.f, c0=0.f,c1=0.f,c2=0.f,c3=0.f;
    for (int j0 = 0; j0 < nb; j0 += 16) {
        const int cnt = min(nb - j0, 16);
        const int idx = (q < cnt) ? srcs[beg + j0 + q] : 0;
        int t = 0;
        for (; t + 3 < cnt; t += 4) {
            int s0 = __shfl(idx, gbase + t);
            int s1 = __shfl(idx, gbase + t + 1);
            int s2 = __shfl(idx, gbase + t + 2);
            int s3 = __shfl(idx, gbase + t + 3);
            const float4 v0 = *reinterpret_cast<const float4*>(rows + (size_t)s0 * 64 + q * 4);
            const float4 v1 = *reinterpret_cast<const float4*>(rows + (size_t)s1 * 64 + q * 4);
            const float4 v2 = *reinterpret_cast<const float4*>(rows + (size_t)s2 * 64 + q * 4);
            const float4 v3 = *reinterpret_cast<const float4*>(rows + (size_t)s3 * 64 + q * 4);
            a0 += v0.x + v2.x; a1 += v0.y + v2.y; a2 += v0.z + v2.z; a3 += v0.w + v2.w;
            c0 += v1.x + v3.x; c1 += v1.y + v3.y; c2 += v1.z + v3.z; c3 += v1.w + v3.w;
        }
        for (; t < cnt; ++t) {
            int s = __shfl(idx, gbase + t);
            const float4 v = *reinterpret_cast<const float4*>(rows + (size_t)s * 64 + q * 4);
            a0 += v.x; a1 += v.y; a2 += v.z; a3 += v.w;
        }
    }
    const float inv = 1.0f / (float)max(nb, 1);
    float4 r;
    r.x = (a0 + c0) * inv; r.y = (a1 + c1) * inv;
    r.z = (a2 + c2) * inv; r.w = (a3 + c3) * inv;
    *reinterpret_cast<float4*>(aggm + (size_t)node * 64 + q * 4) = r;
}

// ---------------------------------------------------------------------------
// K5: dense layer.  Wave-per-node (4/block).  Reads aggm (already mean) & x.
//   h     = relu(aggm @ W1l + x @ W1r + b1)        (registers only)
//   hW2lp = h @ W2l   (stride 64, features 40..63 zero-padded)
//   base  = h @ W2r + b2                            (stride 40)
// ---------------------------------------------------------------------------
__global__ __launch_bounds__(256) void k_dense1(
    const float* __restrict__ x,    const float* __restrict__ aggm,
    const float* __restrict__ W1l,  const float* __restrict__ W1r,
    const float* __restrict__ b1,   const float* __restrict__ W2l,
    const float* __restrict__ W2r,  const float* __restrict__ b2,
    float* __restrict__ hW2lp, float* __restrict__ base)
{
    __shared__ float sW1l[64 * 64];
    __shared__ float sW1r[64 * 64];
    __shared__ float sW2l[64 * 40];
    __shared__ float sW2r[64 * 40];
    __shared__ float sB1[64];
    __shared__ float sB2[40];
    for (int i = threadIdx.x; i < 64 * 64; i += 256) { sW1l[i] = W1l[i]; sW1r[i] = W1r[i]; }
    for (int i = threadIdx.x; i < 64 * 40; i += 256) { sW2l[i] = W2l[i]; sW2r[i] = W2r[i]; }
    if (threadIdx.x < 64) sB1[threadIdx.x] = b1[threadIdx.x];
    if (threadIdx.x < 40) sB2[threadIdx.x] = b2[threadIdx.x];
    __syncthreads();

    const int w    = threadIdx.x >> 6;
    const int lane = threadIdx.x & 63;
    const int node = blockIdx.x * 4 + w;          // grid = NN/4 exactly

    const float aval = aggm[(size_t)node * 64 + lane];
    const float xval = x[(size_t)node * 64 + lane];

    float accA = sB1[lane], accB = 0.0f;
    #pragma unroll
    for (int k = 0; k < 64; ++k) {
        accA += __shfl(aval, k) * sW1l[k * 64 + lane];
        accB += __shfl(xval, k) * sW1r[k * 64 + lane];
    }
    const float hv = fmaxf(accA + accB, 0.0f);

    const int li = lane < 40 ? lane : 0;
    float acc2 = 0.0f, acc3 = 0.0f;
    #pragma unroll
    for (int k = 0; k < 64; ++k) {
        const float hb = __shfl(hv, k);
        acc2 += hb * sW2l[k * 40 + li];
        acc3 += hb * sW2r[k * 40 + li];
    }
    hW2lp[(size_t)node * 64 + lane] = (lane < 40) ? acc2 : 0.0f;
    if (lane < 40) base[(size_t)node * 40 + lane] = acc3 + sB2[lane];
}

// ---------------------------------------------------------------------------
// K6: gather-mean over hW2lp (stride 64, 40 valid) + fused final add:
//   out[node] = mean_{s in N(node)} hW2lp[s][0:40] + base[node]
// ---------------------------------------------------------------------------
__global__ __launch_bounds__(256, 8) void k_gather2(
    const float* __restrict__ rows, const int* __restrict__ rowptr,
    const int* __restrict__ srcs, const float* __restrict__ base,
    float* __restrict__ out)
{
    const int lane  = threadIdx.x & 63;
    const int w     = threadIdx.x >> 6;
    const int q     = lane & 15;
    const int gbase = lane & 48;
    const int node  = blockIdx.x * 16 + w * 4 + (lane >> 4);

    const int beg = rowptr[node];
    const int nb  = rowptr[node + 1] - beg;

    float a0=0.f,a1=0.f,a2=0.f,a3=0.f, c0=0.f,c1=0.f,c2=0.f,c3=0.f;
    for (int j0 = 0; j0 < nb; j0 += 16) {
        const int cnt = min(nb - j0, 16);
        const int idx = (q < cnt) ? srcs[beg + j0 + q] : 0;
        int t = 0;
        for (; t + 3 < cnt; t += 4) {
            int s0 = __shfl(idx, gbase + t);
            int s1 = __shfl(idx, gbase + t + 1);
            int s2 = __shfl(idx, gbase + t + 2);
            int s3 = __shfl(idx, gbase + t + 3);
            const float4 v0 = *reinterpret_cast<const float4*>(rows + (size_t)s0 * 64 + q * 4);
            const float4 v1 = *reinterpret_cast<const float4*>(rows + (size_t)s1 * 64 + q * 4);
            const float4 v2 = *reinterpret_cast<const float4*>(rows + (size_t)s2 * 64 + q * 4);
            const float4 v3 = *reinterpret_cast<const float4*>(rows + (size_t)s3 * 64 + q * 4);
            a0 += v0.x + v2.x; a1 += v0.y + v2.y; a2 += v0.z + v2.z; a3 += v0.w + v2.w;
            c0 += v1.x + v3.x; c1 += v1.y + v3.y; c2 += v1.z + v3.z; c3 += v1.w + v3.w;
        }
        for (; t < cnt; ++t) {
            int s = __shfl(idx, gbase + t);
            const float4 v = *reinterpret_cast<const float4*>(rows + (size_t)s * 64 + q * 4);
            a0 += v.x; a1 += v.y; a2 += v.z; a3 += v.w;
        }
    }
    if (q < 10) {                                   // features 0..39 only
        const float inv = 1.0f / (float)max(nb, 1);
        const float4 bb = *reinterpret_cast<const float4*>(base + (size_t)node * 40 + q * 4);
        float4 r;
        r.x = (a0 + c0) * inv + bb.x; r.y = (a1 + c1) * inv + bb.y;
        r.z = (a2 + c2) * inv + bb.z; r.w = (a3 + c3) * inv + bb.w;
        *reinterpret_cast<float4*>(out + (size_t)node * 40 + q * 4) = r;
    }
}

// ---------------------------------------------------------------------------
// Workspace (4-byte units):
//   [0, NN)              deg_i (int)
//   [NN, 2NN)            cursor (int)
//   [2NN, 3NN+8)         rowptr (int, NN+1 used)
//   [3NN+8, 3NN+8+EE)    srcs (int)
//   then floats: aggm (NN*64), hW2lp (NN*64), base (NN*40).  ~72.4 MB.
//   Only deg_i+cursor (800KB) zeroed per call.
// ---------------------------------------------------------------------------
extern "C" void kernel_launch(void* const* d_in, const int* in_sizes, int n_in,
                              void* d_out, int out_size, void* d_ws, size_t ws_size,
                              hipStream_t stream) {
    const float* x   = (const float*)d_in[0];
    const int*   ei  = (const int*)  d_in[1];
    const float* W1l = (const float*)d_in[2];
    const float* W1r = (const float*)d_in[3];
    const float* b1  = (const float*)d_in[4];
    const float* W2l = (const float*)d_in[5];
    const float* W2r = (const float*)d_in[6];
    const float* b2  = (const float*)d_in[7];
    float* out = (float*)d_out;

    int*   wsi    = (int*)d_ws;
    int*   deg_i  = wsi;
    int*   cursor = wsi + NN;
    int*   rowptr = wsi + 2 * NN;
    int*   srcs   = wsi + 3 * NN + 8;
    float* aggm   = (float*)(wsi + 3 * NN + 8 + EE);
    float* hW2lp  = aggm  + (size_t)NN * 64;
    float* base   = hW2lp + (size_t)NN * 64;

    hipMemsetAsync(d_ws, 0, sizeof(int) * (size_t)2 * NN, stream);

    k_hist<<<(EE + 255) / 256, 256, 0, stream>>>(ei, deg_i);
    k_scan<<<1, SCAN_T, 0, stream>>>(deg_i, rowptr);
    k_fill<<<(EE + 255) / 256, 256, 0, stream>>>(ei, rowptr, cursor, srcs);
    k_gather1<<<NN / 16, 256, 0, stream>>>(x, rowptr, srcs, aggm);
    k_dense1<<<NN / 4, 256, 0, stream>>>(x, aggm, W1l, W1r, b1, W2l, W2r, b2, hW2lp, base);
    k_gather2<<<NN / 16, 256, 0, stream>>>(hW2lp, rowptr, srcs, base, out);
}

// Round 4
// 406.652 us; speedup vs baseline: 4.6881x; 1.7574x over previous
//
#include <hip/hip_runtime.h>

#define NN 100000
#define EE 1000000

typedef unsigned short ushort_t;
typedef short bf16x8 __attribute__((ext_vector_type(8)));
typedef float f32x4 __attribute__((ext_vector_type(4)));

// ---- bf16 helpers (RTNE pack, shift unpack) -------------------------------
__device__ __forceinline__ unsigned short f2bf(float f) {
    unsigned u = __builtin_bit_cast(unsigned, f);
    u += 0x7fffu + ((u >> 16) & 1u);
    return (unsigned short)(u >> 16);
}
__device__ __forceinline__ float bflo(unsigned u) {   // low ushort -> float
    return __builtin_bit_cast(float, u << 16);
}
__device__ __forceinline__ float bfhi(unsigned u) {   // high ushort -> float
    return __builtin_bit_cast(float, u & 0xffff0000u);
}
__device__ __forceinline__ unsigned pk2(float a, float b) {
    return (unsigned)f2bf(a) | ((unsigned)f2bf(b) << 16);
}

// ---------------------------------------------------------------------------
// K0: cast x (f32) -> xb (bf16).  8 elems/thread.
// ---------------------------------------------------------------------------
__global__ __launch_bounds__(256) void k_cast(
    const float* __restrict__ x, ushort_t* __restrict__ xb)
{
    size_t t = (size_t)blockIdx.x * 256 + threadIdx.x;   // grid covers NN*64/8
    const float4 v0 = *reinterpret_cast<const float4*>(x + t * 8);
    const float4 v1 = *reinterpret_cast<const float4*>(x + t * 8 + 4);
    uint4 r;
    r.x = pk2(v0.x, v0.y); r.y = pk2(v0.z, v0.w);
    r.z = pk2(v1.x, v1.y); r.w = pk2(v1.z, v1.w);
    *reinterpret_cast<uint4*>(xb + t * 8) = r;
}

// ---------------------------------------------------------------------------
// K1: histogram of dst -> deg_i
// ---------------------------------------------------------------------------
__global__ __launch_bounds__(256) void k_hist(
    const int* __restrict__ ei, int* __restrict__ deg_i)
{
    int e = blockIdx.x * blockDim.x + threadIdx.x;
    if (e < EE) atomicAdd(deg_i + ei[EE + e], 1);
}

// ---------------------------------------------------------------------------
// K2: exclusive prefix sum of deg_i -> rowptr[NN+1].  Single 1024-thread block.
// ---------------------------------------------------------------------------
#define SCAN_T 1024
#define SCAN_CH 98
__global__ __launch_bounds__(SCAN_T) void k_scan(
    const int* __restrict__ deg_i, int* __restrict__ rowptr)
{
    __shared__ int part[SCAN_T];
    const int t = threadIdx.x;
    const int base = t * SCAN_CH;
    int s = 0;
    for (int i = 0; i < SCAN_CH; ++i) {
        int idx = base + i;
        if (idx < NN) s += deg_i[idx];
    }
    part[t] = s;
    __syncthreads();
    for (int off = 1; off < SCAN_T; off <<= 1) {
        int v = (t >= off) ? part[t - off] : 0;
        __syncthreads();
        part[t] += v;
        __syncthreads();
    }
    int run = (t == 0) ? 0 : part[t - 1];
    for (int i = 0; i < SCAN_CH; ++i) {
        int idx = base + i;
        if (idx < NN) { rowptr[idx] = run; run += deg_i[idx]; }
    }
    if (t == SCAN_T - 1) rowptr[NN] = run;
}

// ---------------------------------------------------------------------------
// K3: bucket fill: srcs[rowptr[dst] + cursor[dst]++] = src
// ---------------------------------------------------------------------------
__global__ __launch_bounds__(256) void k_fill(
    const int* __restrict__ ei, const int* __restrict__ rowptr,
    int* __restrict__ cursor, int* __restrict__ srcs)
{
    int e = blockIdx.x * blockDim.x + threadIdx.x;
    if (e >= EE) return;
    int dst = ei[EE + e];
    int pos = rowptr[dst] + atomicAdd(cursor + dst, 1);
    srcs[pos] = ei[e];
}

// ---------------------------------------------------------------------------
// K4: gather-mean over bf16 stride-64 rows (128B/row).  8 lanes/node x 16B,
// 8 nodes/wave, 32 nodes/block, no LDS, 4-way unrolled.  Output bf16 mean.
// ---------------------------------------------------------------------------
__global__ __launch_bounds__(256, 8) void k_gather1(
    const ushort_t* __restrict__ rows, const int* __restrict__ rowptr,
    const int* __restrict__ srcs, ushort_t* __restrict__ aggm)
{
    const int lane = threadIdx.x & 63;
    const int w    = threadIdx.x >> 6;
    const int p    = lane & 7;
    const int gb   = lane & 56;
    const int node = blockIdx.x * 32 + w * 8 + (lane >> 3);

    const int beg = rowptr[node];
    const int nb  = rowptr[node + 1] - beg;

    float a0=0,a1=0,a2=0,a3=0,a4=0,a5=0,a6=0,a7=0;
    for (int j0 = 0; j0 < nb; j0 += 8) {
        const int cnt = min(nb - j0, 8);
        const int idx = (p < cnt) ? srcs[beg + j0 + p] : 0;
        int t = 0;
        for (; t + 3 < cnt; t += 4) {
            int s0 = __shfl(idx, gb + t),     s1 = __shfl(idx, gb + t + 1);
            int s2 = __shfl(idx, gb + t + 2), s3 = __shfl(idx, gb + t + 3);
            const uint4 v0 = *reinterpret_cast<const uint4*>(rows + (size_t)s0 * 64 + p * 8);
            const uint4 v1 = *reinterpret_cast<const uint4*>(rows + (size_t)s1 * 64 + p * 8);
            const uint4 v2 = *reinterpret_cast<const uint4*>(rows + (size_t)s2 * 64 + p * 8);
            const uint4 v3 = *reinterpret_cast<const uint4*>(rows + (size_t)s3 * 64 + p * 8);
            a0 += bflo(v0.x)+bflo(v1.x)+bflo(v2.x)+bflo(v3.x);
            a1 += bfhi(v0.x)+bfhi(v1.x)+bfhi(v2.x)+bfhi(v3.x);
            a2 += bflo(v0.y)+bflo(v1.y)+bflo(v2.y)+bflo(v3.y);
            a3 += bfhi(v0.y)+bfhi(v1.y)+bfhi(v2.y)+bfhi(v3.y);
            a4 += bflo(v0.z)+bflo(v1.z)+bflo(v2.z)+bflo(v3.z);
            a5 += bfhi(v0.z)+bfhi(v1.z)+bfhi(v2.z)+bfhi(v3.z);
            a6 += bflo(v0.w)+bflo(v1.w)+bflo(v2.w)+bflo(v3.w);
            a7 += bfhi(v0.w)+bfhi(v1.w)+bfhi(v2.w)+bfhi(v3.w);
        }
        for (; t < cnt; ++t) {
            int s = __shfl(idx, gb + t);
            const uint4 v = *reinterpret_cast<const uint4*>(rows + (size_t)s * 64 + p * 8);
            a0 += bflo(v.x); a1 += bfhi(v.x); a2 += bflo(v.y); a3 += bfhi(v.y);
            a4 += bflo(v.z); a5 += bfhi(v.z); a6 += bflo(v.w); a7 += bfhi(v.w);
        }
    }
    const float inv = 1.0f / (float)max(nb, 1);
    uint4 r;
    r.x = pk2(a0*inv, a1*inv); r.y = pk2(a2*inv, a3*inv);
    r.z = pk2(a4*inv, a5*inv); r.w = pk2(a6*inv, a7*inv);
    *reinterpret_cast<uint4*>(aggm + (size_t)node * 64 + p * 8) = r;
}

// ---------------------------------------------------------------------------
// K5: MFMA dense layer.  256 thr = 4 waves; wave owns 16 nodes.
//   GEMM1: [aggm_b | xb] (16x128) @ W1cat (128x64) -> relu -> h (bf16 LDS)
//   GEMM2: h (16x64) @ [W2l | W2r] (64x80)
//     feats 0..39  -> hW2b (bf16, stride 64; cols 40..63 pre-zeroed)
//     feats 40..79 -> base = val + b2 (f32, stride 40)
// Fragment maps (m89/m97): A[row=l&15][k=8*(l>>4)+j], BT[col=l&15][k=8*(l>>4)+j],
//                          D[row=(l>>4)*4+r][col=l&15].
// LDS strides padded (136/72 bf16) -> <=2-way bank aliasing on ds_read_b128.
// ---------------------------------------------------------------------------
__global__ __launch_bounds__(256) void k_dense1(
    const ushort_t* __restrict__ xb, const ushort_t* __restrict__ aggm_b,
    const float* __restrict__ W1l, const float* __restrict__ W1r,
    const float* __restrict__ b1,  const float* __restrict__ W2l,
    const float* __restrict__ W2r, const float* __restrict__ b2,
    ushort_t* __restrict__ hW2b, float* __restrict__ base)
{
    __shared__ __align__(16) ushort_t sW1T[64 * 136];
    __shared__ __align__(16) ushort_t sW2T[80 * 72];
    __shared__ __align__(16) ushort_t sH[4][16 * 72];
    __shared__ float sB1[64];
    __shared__ float sB2[40];

    const int t = threadIdx.x;
    {   // stage W1T[n][k] = (k<64 ? W1l[k][n] : W1r[k-64][n]) as bf16
        const int n = t & 63, kr = t >> 6;
        for (int i = 0; i < 32; ++i) {
            int k = kr * 32 + i;
            float v = (k < 64) ? W1l[k * 64 + n] : W1r[(k - 64) * 64 + n];
            sW1T[n * 136 + k] = f2bf(v);
        }
    }
    for (int idx = t; idx < 80 * 64; idx += 256) {   // W2T[n2][k]
        int n2 = idx % 80, k = idx / 80;
        float v = (n2 < 40) ? W2l[k * 40 + n2] : W2r[k * 40 + (n2 - 40)];
        sW2T[n2 * 72 + k] = f2bf(v);
    }
    if (t < 64) sB1[t] = b1[t];
    if (t < 40) sB2[t] = b2[t];
    __syncthreads();

    const int w = t >> 6, lane = t & 63;
    const int l15 = lane & 15, g = lane >> 4;
    const int nbase = blockIdx.x * 64 + w * 16;
    const int arow = min(nbase + l15, NN - 1);        // clamp for tail block

    // ---- GEMM1 ----
    const f32x4 zero = {0.f, 0.f, 0.f, 0.f};
    f32x4 acc0 = zero, acc1 = zero, acc2_ = zero, acc3 = zero;
    bf16x8 afr[4];
    #pragma unroll
    for (int ks = 0; ks < 4; ++ks) {
        const int k0 = ks * 32;
        const ushort_t* src = (k0 < 64)
            ? (aggm_b + (size_t)arow * 64 + k0 + 8 * g)
            : (xb     + (size_t)arow * 64 + (k0 - 64) + 8 * g);
        afr[ks] = *reinterpret_cast<const bf16x8*>(src);
    }
    #pragma unroll
    for (int ks = 0; ks < 4; ++ks) {
        const bf16x8 b0 = *reinterpret_cast<const bf16x8*>(&sW1T[( 0 + l15) * 136 + ks * 32 + 8 * g]);
        const bf16x8 b1f = *reinterpret_cast<const bf16x8*>(&sW1T[(16 + l15) * 136 + ks * 32 + 8 * g]);
        const bf16x8 b2f = *reinterpret_cast<const bf16x8*>(&sW1T[(32 + l15) * 136 + ks * 32 + 8 * g]);
        const bf16x8 b3f = *reinterpret_cast<const bf16x8*>(&sW1T[(48 + l15) * 136 + ks * 32 + 8 * g]);
        acc0  = __builtin_amdgcn_mfma_f32_16x16x32_bf16(afr[ks], b0,  acc0,  0, 0, 0);
        acc1  = __builtin_amdgcn_mfma_f32_16x16x32_bf16(afr[ks], b1f, acc1,  0, 0, 0);
        acc2_ = __builtin_amdgcn_mfma_f32_16x16x32_bf16(afr[ks], b2f, acc2_, 0, 0, 0);
        acc3  = __builtin_amdgcn_mfma_f32_16x16x32_bf16(afr[ks], b3f, acc3,  0, 0, 0);
    }

    // h = relu(acc + b1) -> per-wave LDS tile (bf16), rows = node-within-16
    {
        const float bb0 = sB1[ 0 + l15], bb1 = sB1[16 + l15];
        const float bb2 = sB1[32 + l15], bb3 = sB1[48 + l15];
        #pragma unroll
        for (int r = 0; r < 4; ++r) {
            const int row = g * 4 + r;
            sH[w][row * 72 +  0 + l15] = f2bf(fmaxf(acc0[r]  + bb0, 0.f));
            sH[w][row * 72 + 16 + l15] = f2bf(fmaxf(acc1[r]  + bb1, 0.f));
            sH[w][row * 72 + 32 + l15] = f2bf(fmaxf(acc2_[r] + bb2, 0.f));
            sH[w][row * 72 + 48 + l15] = f2bf(fmaxf(acc3[r]  + bb3, 0.f));
        }
    }
    __syncthreads();

    // ---- GEMM2 ----
    bf16x8 a2[2];
    a2[0] = *reinterpret_cast<const bf16x8*>(&sH[w][l15 * 72 +  0 + 8 * g]);
    a2[1] = *reinterpret_cast<const bf16x8*>(&sH[w][l15 * 72 + 32 + 8 * g]);
    f32x4 o[5] = {zero, zero, zero, zero, zero};
    #pragma unroll
    for (int nt = 0; nt < 5; ++nt) {
        #pragma unroll
        for (int ks = 0; ks < 2; ++ks) {
            const bf16x8 bfr = *reinterpret_cast<const bf16x8*>(
                &sW2T[(nt * 16 + l15) * 72 + ks * 32 + 8 * g]);
            o[nt] = __builtin_amdgcn_mfma_f32_16x16x32_bf16(a2[ks], bfr, o[nt], 0, 0, 0);
        }
    }

    // ---- store ----
    #pragma unroll
    for (int nt = 0; nt < 5; ++nt) {
        const int f2 = nt * 16 + l15;
        #pragma unroll
        for (int r = 0; r < 4; ++r) {
            const int node = nbase + g * 4 + r;
            if (node < NN) {
                const float v = o[nt][r];
                if (f2 < 40) hW2b[(size_t)node * 64 + f2] = f2bf(v);
                else         base[(size_t)node * 40 + (f2 - 40)] = v + sB2[f2 - 40];
            }
        }
    }
}

// ---------------------------------------------------------------------------
// K6: gather-mean over hW2b (bf16 stride-64, cols 40..63 zero) + base -> out
// ---------------------------------------------------------------------------
__global__ __launch_bounds__(256, 8) void k_gather2(
    const ushort_t* __restrict__ rows, const int* __restrict__ rowptr,
    const int* __restrict__ srcs, const float* __restrict__ base,
    float* __restrict__ out)
{
    const int lane = threadIdx.x & 63;
    const int w    = threadIdx.x >> 6;
    const int p    = lane & 7;
    const int gb   = lane & 56;
    const int node = blockIdx.x * 32 + w * 8 + (lane >> 3);

    const int beg = rowptr[node];
    const int nb  = rowptr[node + 1] - beg;

    float a0=0,a1=0,a2=0,a3=0,a4=0,a5=0,a6=0,a7=0;
    for (int j0 = 0; j0 < nb; j0 += 8) {
        const int cnt = min(nb - j0, 8);
        const int idx = (p < cnt) ? srcs[beg + j0 + p] : 0;
        int t = 0;
        for (; t + 3 < cnt; t += 4) {
            int s0 = __shfl(idx, gb + t),     s1 = __shfl(idx, gb + t + 1);
            int s2 = __shfl(idx, gb + t + 2), s3 = __shfl(idx, gb + t + 3);
            const uint4 v0 = *reinterpret_cast<const uint4*>(rows + (size_t)s0 * 64 + p * 8);
            const uint4 v1 = *reinterpret_cast<const uint4*>(rows + (size_t)s1 * 64 + p * 8);
            const uint4 v2 = *reinterpret_cast<const uint4*>(rows + (size_t)s2 * 64 + p * 8);
            const uint4 v3 = *reinterpret_cast<const uint4*>(rows + (size_t)s3 * 64 + p * 8);
            a0 += bflo(v0.x)+bflo(v1.x)+bflo(v2.x)+bflo(v3.x);
            a1 += bfhi(v0.x)+bfhi(v1.x)+bfhi(v2.x)+bfhi(v3.x);
            a2 += bflo(v0.y)+bflo(v1.y)+bflo(v2.y)+bflo(v3.y);
            a3 += bfhi(v0.y)+bfhi(v1.y)+bfhi(v2.y)+bfhi(v3.y);
            a4 += bflo(v0.z)+bflo(v1.z)+bflo(v2.z)+bflo(v3.z);
            a5 += bfhi(v0.z)+bfhi(v1.z)+bfhi(v2.z)+bfhi(v3.z);
            a6 += bflo(v0.w)+bflo(v1.w)+bflo(v2.w)+bflo(v3.w);
            a7 += bfhi(v0.w)+bfhi(v1.w)+bfhi(v2.w)+bfhi(v3.w);
        }
        for (; t < cnt; ++t) {
            int s = __shfl(idx, gb + t);
            const uint4 v = *reinterpret_cast<const uint4*>(rows + (size_t)s * 64 + p * 8);
            a0 += bflo(v.x); a1 += bfhi(v.x); a2 += bflo(v.y); a3 += bfhi(v.y);
            a4 += bflo(v.z); a5 += bfhi(v.z); a6 += bflo(v.w); a7 += bfhi(v.w);
        }
    }
    if (p < 5) {
        const float inv = 1.0f / (float)max(nb, 1);
        const float4 bb0 = *reinterpret_cast<const float4*>(base + (size_t)node * 40 + p * 8);
        const float4 bb1 = *reinterpret_cast<const float4*>(base + (size_t)node * 40 + p * 8 + 4);
        float4 r0, r1;
        r0.x = a0*inv + bb0.x; r0.y = a1*inv + bb0.y; r0.z = a2*inv + bb0.z; r0.w = a3*inv + bb0.w;
        r1.x = a4*inv + bb1.x; r1.y = a5*inv + bb1.y; r1.z = a6*inv + bb1.z; r1.w = a7*inv + bb1.w;
        *reinterpret_cast<float4*>(out + (size_t)node * 40 + p * 8)     = r0;
        *reinterpret_cast<float4*>(out + (size_t)node * 40 + p * 8 + 4) = r1;
    }
}

// ---------------------------------------------------------------------------
// Workspace (4-byte units unless noted):
//   [0, NN)            deg_i (int)
//   [NN, 2NN)          cursor (int)
//   [2NN, 3NN+8)       rowptr (int)
//   [3NN+8, +EE)       srcs (int)
//   then bf16 arrays: xb (NN*64), aggm_b (NN*64), hW2b (NN*64)
//   then f32: base (NN*40).   Total ~59.6 MB.
//   Per call: zero deg_i+cursor (800KB) and hW2b (12.8MB).
// ---------------------------------------------------------------------------
extern "C" void kernel_launch(void* const* d_in, const int* in_sizes, int n_in,
                              void* d_out, int out_size, void* d_ws, size_t ws_size,
                              hipStream_t stream) {
    const float* x   = (const float*)d_in[0];
    const int*   ei  = (const int*)  d_in[1];
    const float* W1l = (const float*)d_in[2];
    const float* W1r = (const float*)d_in[3];
    const float* b1  = (const float*)d_in[4];
    const float* W2l = (const float*)d_in[5];
    const float* W2r = (const float*)d_in[6];
    const float* b2  = (const float*)d_in[7];
    float* out = (float*)d_out;

    int* wsi = (int*)d_ws;
    int* deg_i  = wsi;
    int* cursor = wsi + NN;
    int* rowptr = wsi + 2 * NN;
    int* srcs   = wsi + 3 * NN + 8;
    ushort_t* xb     = (ushort_t*)(wsi + 3 * NN + 8 + EE);
    ushort_t* aggm_b = xb     + (size_t)NN * 64;
    ushort_t* hW2b   = aggm_b + (size_t)NN * 64;
    float*    base   = (float*)(hW2b + (size_t)NN * 64);

    hipMemsetAsync(d_ws, 0, sizeof(int) * (size_t)2 * NN, stream);
    hipMemsetAsync(hW2b, 0, sizeof(ushort_t) * (size_t)NN * 64, stream);

    k_cast<<<NN * 64 / 8 / 256, 256, 0, stream>>>(x, xb);
    k_hist<<<(EE + 255) / 256, 256, 0, stream>>>(ei, deg_i);
    k_scan<<<1, SCAN_T, 0, stream>>>(deg_i, rowptr);
    k_fill<<<(EE + 255) / 256, 256, 0, stream>>>(ei, rowptr, cursor, srcs);
    k_gather1<<<NN / 32, 256, 0, stream>>>(xb, rowptr, srcs, aggm_b);
    k_dense1<<<(NN + 63) / 64, 256, 0, stream>>>(xb, aggm_b, W1l, W1r, b1,
                                                 W2l, W2r, b2, hW2b, base);
    k_gather2<<<NN / 32, 256, 0, stream>>>(hW2b, rowptr, srcs, base, out);
}

// Round 5
// 221.298 us; speedup vs baseline: 8.6148x; 1.8376x over previous
//
#include <hip/hip_runtime.h>

#define NN 100000
#define EE 1000000
#define NB 98           // ceil(NN / 1024) scan blocks

typedef unsigned short ushort_t;
typedef short bf16x8 __attribute__((ext_vector_type(8)));
typedef float f32x4 __attribute__((ext_vector_type(4)));

// ---- bf16 helpers (RTNE pack, shift unpack) -------------------------------
__device__ __forceinline__ unsigned short f2bf(float f) {
    unsigned u = __builtin_bit_cast(unsigned, f);
    u += 0x7fffu + ((u >> 16) & 1u);
    return (unsigned short)(u >> 16);
}
__device__ __forceinline__ float bflo(unsigned u) {
    return __builtin_bit_cast(float, u << 16);
}
__device__ __forceinline__ float bfhi(unsigned u) {
    return __builtin_bit_cast(float, u & 0xffff0000u);
}
__device__ __forceinline__ unsigned pk2(float a, float b) {
    return (unsigned)f2bf(a) | ((unsigned)f2bf(b) << 16);
}

// ---------------------------------------------------------------------------
// K0: cast x (f32) -> xb (bf16).  8 elems/thread.
// ---------------------------------------------------------------------------
__global__ __launch_bounds__(256) void k_cast(
    const float* __restrict__ x, ushort_t* __restrict__ xb)
{
    size_t t = (size_t)blockIdx.x * 256 + threadIdx.x;
    const float4 v0 = *reinterpret_cast<const float4*>(x + t * 8);
    const float4 v1 = *reinterpret_cast<const float4*>(x + t * 8 + 4);
    uint4 r;
    r.x = pk2(v0.x, v0.y); r.y = pk2(v0.z, v0.w);
    r.z = pk2(v1.x, v1.y); r.w = pk2(v1.z, v1.w);
    *reinterpret_cast<uint4*>(xb + t * 8) = r;
}

// ---------------------------------------------------------------------------
// K1: histogram of dst -> deg_i
// ---------------------------------------------------------------------------
__global__ __launch_bounds__(256) void k_hist(
    const int* __restrict__ ei, int* __restrict__ deg_i)
{
    int e = blockIdx.x * blockDim.x + threadIdx.x;
    if (e < EE) atomicAdd(deg_i + ei[EE + e], 1);
}

// ---------------------------------------------------------------------------
// K2a: per-block (1024-int chunk) sum -> bsum[b]
// ---------------------------------------------------------------------------
__global__ __launch_bounds__(256) void k_scanA(
    const int* __restrict__ deg_i, int* __restrict__ bsum)
{
    const int b = blockIdx.x, t = threadIdx.x;
    const int i = b * 1024 + t * 4;
    int s = 0;
    if (i + 3 < NN) {
        const int4 v = *reinterpret_cast<const int4*>(deg_i + i);
        s = v.x + v.y + v.z + v.w;
    } else {
        for (int j = 0; j < 4; ++j) if (i + j < NN) s += deg_i[i + j];
    }
    #pragma unroll
    for (int off = 32; off; off >>= 1) s += __shfl_down(s, off);
    __shared__ int red[4];
    if ((t & 63) == 0) red[t >> 6] = s;
    __syncthreads();
    if (t == 0) bsum[b] = red[0] + red[1] + red[2] + red[3];
}

// ---------------------------------------------------------------------------
// K2b: exclusive scan of bsum[NB] -> boff[NB]; rowptr[NN] = total (== EE)
// ---------------------------------------------------------------------------
__global__ __launch_bounds__(128) void k_scanB(
    const int* __restrict__ bsum, int* __restrict__ boff, int* __restrict__ rowptr)
{
    __shared__ int part[128];
    const int t = threadIdx.x;
    const int v = (t < NB) ? bsum[t] : 0;
    part[t] = v;
    __syncthreads();
    for (int off = 1; off < 128; off <<= 1) {
        int u = (t >= off) ? part[t - off] : 0;
        __syncthreads();
        part[t] += u;
        __syncthreads();
    }
    if (t < NB) boff[t] = part[t] - v;
    if (t == 127) rowptr[NN] = part[127];
}

// ---------------------------------------------------------------------------
// K2c: block-local exclusive scan + boff[b] -> rowptr
// ---------------------------------------------------------------------------
__global__ __launch_bounds__(256) void k_scanC(
    const int* __restrict__ deg_i, const int* __restrict__ boff,
    int* __restrict__ rowptr)
{
    const int b = blockIdx.x, t = threadIdx.x;
    const int i = b * 1024 + t * 4;
    int e0 = 0, e1 = 0, e2 = 0, e3 = 0;
    if (i + 3 < NN) {
        const int4 v = *reinterpret_cast<const int4*>(deg_i + i);
        e0 = v.x; e1 = v.y; e2 = v.z; e3 = v.w;
    } else {
        if (i     < NN) e0 = deg_i[i];
        if (i + 1 < NN) e1 = deg_i[i + 1];
        if (i + 2 < NN) e2 = deg_i[i + 2];
        if (i + 3 < NN) e3 = deg_i[i + 3];
    }
    const int s = e0 + e1 + e2 + e3;
    __shared__ int part[256];
    part[t] = s;
    __syncthreads();
    for (int off = 1; off < 256; off <<= 1) {
        int u = (t >= off) ? part[t - off] : 0;
        __syncthreads();
        part[t] += u;
        __syncthreads();
    }
    int excl = part[t] - s + boff[b];
    if (i     < NN) rowptr[i]     = excl;
    if (i + 1 < NN) rowptr[i + 1] = excl + e0;
    if (i + 2 < NN) rowptr[i + 2] = excl + e0 + e1;
    if (i + 3 < NN) rowptr[i + 3] = excl + e0 + e1 + e2;
}

// ---------------------------------------------------------------------------
// K3: bucket fill: srcs[rowptr[dst] + cursor[dst]++] = src
// ---------------------------------------------------------------------------
__global__ __launch_bounds__(256) void k_fill(
    const int* __restrict__ ei, const int* __restrict__ rowptr,
    int* __restrict__ cursor, int* __restrict__ srcs)
{
    int e = blockIdx.x * blockDim.x + threadIdx.x;
    if (e >= EE) return;
    int dst = ei[EE + e];
    int pos = rowptr[dst] + atomicAdd(cursor + dst, 1);
    srcs[pos] = ei[e];
}

// ---------------------------------------------------------------------------
// K4: gather-mean over bf16 stride-64 rows (128B/row).  8 lanes/node x 16B,
// 8 nodes/wave, 32 nodes/block, no LDS, 4-way unrolled.  Output bf16 mean.
// ---------------------------------------------------------------------------
__global__ __launch_bounds__(256, 8) void k_gather1(
    const ushort_t* __restrict__ rows, const int* __restrict__ rowptr,
    const int* __restrict__ srcs, ushort_t* __restrict__ aggm)
{
    const int lane = threadIdx.x & 63;
    const int w    = threadIdx.x >> 6;
    const int p    = lane & 7;
    const int gb   = lane & 56;
    const int node = blockIdx.x * 32 + w * 8 + (lane >> 3);

    const int beg = rowptr[node];
    const int nb  = rowptr[node + 1] - beg;

    float a0=0,a1=0,a2=0,a3=0,a4=0,a5=0,a6=0,a7=0;
    for (int j0 = 0; j0 < nb; j0 += 8) {
        const int cnt = min(nb - j0, 8);
        const int idx = (p < cnt) ? srcs[beg + j0 + p] : 0;
        int t = 0;
        for (; t + 3 < cnt; t += 4) {
            int s0 = __shfl(idx, gb + t),     s1 = __shfl(idx, gb + t + 1);
            int s2 = __shfl(idx, gb + t + 2), s3 = __shfl(idx, gb + t + 3);
            const uint4 v0 = *reinterpret_cast<const uint4*>(rows + (size_t)s0 * 64 + p * 8);
            const uint4 v1 = *reinterpret_cast<const uint4*>(rows + (size_t)s1 * 64 + p * 8);
            const uint4 v2 = *reinterpret_cast<const uint4*>(rows + (size_t)s2 * 64 + p * 8);
            const uint4 v3 = *reinterpret_cast<const uint4*>(rows + (size_t)s3 * 64 + p * 8);
            a0 += bflo(v0.x)+bflo(v1.x)+bflo(v2.x)+bflo(v3.x);
            a1 += bfhi(v0.x)+bfhi(v1.x)+bfhi(v2.x)+bfhi(v3.x);
            a2 += bflo(v0.y)+bflo(v1.y)+bflo(v2.y)+bflo(v3.y);
            a3 += bfhi(v0.y)+bfhi(v1.y)+bfhi(v2.y)+bfhi(v3.y);
            a4 += bflo(v0.z)+bflo(v1.z)+bflo(v2.z)+bflo(v3.z);
            a5 += bfhi(v0.z)+bfhi(v1.z)+bfhi(v2.z)+bfhi(v3.z);
            a6 += bflo(v0.w)+bflo(v1.w)+bflo(v2.w)+bflo(v3.w);
            a7 += bfhi(v0.w)+bfhi(v1.w)+bfhi(v2.w)+bfhi(v3.w);
        }
        for (; t < cnt; ++t) {
            int s = __shfl(idx, gb + t);
            const uint4 v = *reinterpret_cast<const uint4*>(rows + (size_t)s * 64 + p * 8);
            a0 += bflo(v.x); a1 += bfhi(v.x); a2 += bflo(v.y); a3 += bfhi(v.y);
            a4 += bflo(v.z); a5 += bfhi(v.z); a6 += bflo(v.w); a7 += bfhi(v.w);
        }
    }
    const float inv = 1.0f / (float)max(nb, 1);
    uint4 r;
    r.x = pk2(a0*inv, a1*inv); r.y = pk2(a2*inv, a3*inv);
    r.z = pk2(a4*inv, a5*inv); r.w = pk2(a6*inv, a7*inv);
    *reinterpret_cast<uint4*>(aggm + (size_t)node * 64 + p * 8) = r;
}

// ---------------------------------------------------------------------------
// K5: MFMA dense layer.  256 thr = 4 waves; wave owns 16 nodes.
//   GEMM1: [aggm_b | xb] (16x128) @ W1cat (128x64) -> relu -> h (bf16 LDS)
//   GEMM2: h (16x64) @ [W2l | W2r] (64x80)
//     feats 0..39  -> hW2b (bf16, stride 64; cols 40..63 pre-zeroed)
//     feats 40..79 -> base = val + b2 (f32, stride 40)
// ---------------------------------------------------------------------------
__global__ __launch_bounds__(256) void k_dense1(
    const ushort_t* __restrict__ xb, const ushort_t* __restrict__ aggm_b,
    const float* __restrict__ W1l, const float* __restrict__ W1r,
    const float* __restrict__ b1,  const float* __restrict__ W2l,
    const float* __restrict__ W2r, const float* __restrict__ b2,
    ushort_t* __restrict__ hW2b, float* __restrict__ base)
{
    __shared__ __align__(16) ushort_t sW1T[64 * 136];
    __shared__ __align__(16) ushort_t sW2T[80 * 72];
    __shared__ __align__(16) ushort_t sH[4][16 * 72];
    __shared__ float sB1[64];
    __shared__ float sB2[40];

    const int t = threadIdx.x;
    {
        const int n = t & 63, kr = t >> 6;
        for (int i = 0; i < 32; ++i) {
            int k = kr * 32 + i;
            float v = (k < 64) ? W1l[k * 64 + n] : W1r[(k - 64) * 64 + n];
            sW1T[n * 136 + k] = f2bf(v);
        }
    }
    for (int idx = t; idx < 80 * 64; idx += 256) {
        int n2 = idx % 80, k = idx / 80;
        float v = (n2 < 40) ? W2l[k * 40 + n2] : W2r[k * 40 + (n2 - 40)];
        sW2T[n2 * 72 + k] = f2bf(v);
    }
    if (t < 64) sB1[t] = b1[t];
    if (t < 40) sB2[t] = b2[t];
    __syncthreads();

    const int w = t >> 6, lane = t & 63;
    const int l15 = lane & 15, g = lane >> 4;
    const int nbase = blockIdx.x * 64 + w * 16;
    const int arow = min(nbase + l15, NN - 1);

    const f32x4 zero = {0.f, 0.f, 0.f, 0.f};
    f32x4 acc0 = zero, acc1 = zero, acc2_ = zero, acc3 = zero;
    bf16x8 afr[4];
    #pragma unroll
    for (int ks = 0; ks < 4; ++ks) {
        const int k0 = ks * 32;
        const ushort_t* src = (k0 < 64)
            ? (aggm_b + (size_t)arow * 64 + k0 + 8 * g)
            : (xb     + (size_t)arow * 64 + (k0 - 64) + 8 * g);
        afr[ks] = *reinterpret_cast<const bf16x8*>(src);
    }
    #pragma unroll
    for (int ks = 0; ks < 4; ++ks) {
        const bf16x8 b0  = *reinterpret_cast<const bf16x8*>(&sW1T[( 0 + l15) * 136 + ks * 32 + 8 * g]);
        const bf16x8 b1f = *reinterpret_cast<const bf16x8*>(&sW1T[(16 + l15) * 136 + ks * 32 + 8 * g]);
        const bf16x8 b2f = *reinterpret_cast<const bf16x8*>(&sW1T[(32 + l15) * 136 + ks * 32 + 8 * g]);
        const bf16x8 b3f = *reinterpret_cast<const bf16x8*>(&sW1T[(48 + l15) * 136 + ks * 32 + 8 * g]);
        acc0  = __builtin_amdgcn_mfma_f32_16x16x32_bf16(afr[ks], b0,  acc0,  0, 0, 0);
        acc1  = __builtin_amdgcn_mfma_f32_16x16x32_bf16(afr[ks], b1f, acc1,  0, 0, 0);
        acc2_ = __builtin_amdgcn_mfma_f32_16x16x32_bf16(afr[ks], b2f, acc2_, 0, 0, 0);
        acc3  = __builtin_amdgcn_mfma_f32_16x16x32_bf16(afr[ks], b3f, acc3,  0, 0, 0);
    }

    {
        const float bb0 = sB1[ 0 + l15], bb1 = sB1[16 + l15];
        const float bb2 = sB1[32 + l15], bb3 = sB1[48 + l15];
        #pragma unroll
        for (int r = 0; r < 4; ++r) {
            const int row = g * 4 + r;
            sH[w][row * 72 +  0 + l15] = f2bf(fmaxf(acc0[r]  + bb0, 0.f));
            sH[w][row * 72 + 16 + l15] = f2bf(fmaxf(acc1[r]  + bb1, 0.f));
            sH[w][row * 72 + 32 + l15] = f2bf(fmaxf(acc2_[r] + bb2, 0.f));
            sH[w][row * 72 + 48 + l15] = f2bf(fmaxf(acc3[r]  + bb3, 0.f));
        }
    }
    __syncthreads();

    bf16x8 a2[2];
    a2[0] = *reinterpret_cast<const bf16x8*>(&sH[w][l15 * 72 +  0 + 8 * g]);
    a2[1] = *reinterpret_cast<const bf16x8*>(&sH[w][l15 * 72 + 32 + 8 * g]);
    f32x4 o[5] = {zero, zero, zero, zero, zero};
    #pragma unroll
    for (int nt = 0; nt < 5; ++nt) {
        #pragma unroll
        for (int ks = 0; ks < 2; ++ks) {
            const bf16x8 bfr = *reinterpret_cast<const bf16x8*>(
                &sW2T[(nt * 16 + l15) * 72 + ks * 32 + 8 * g]);
            o[nt] = __builtin_amdgcn_mfma_f32_16x16x32_bf16(a2[ks], bfr, o[nt], 0, 0, 0);
        }
    }

    #pragma unroll
    for (int nt = 0; nt < 5; ++nt) {
        const int f2 = nt * 16 + l15;
        #pragma unroll
        for (int r = 0; r < 4; ++r) {
            const int node = nbase + g * 4 + r;
            if (node < NN) {
                const float v = o[nt][r];
                if (f2 < 40) hW2b[(size_t)node * 64 + f2] = f2bf(v);
                else         base[(size_t)node * 40 + (f2 - 40)] = v + sB2[f2 - 40];
            }
        }
    }
}

// ---------------------------------------------------------------------------
// K6: gather-mean over hW2b (bf16 stride-64, cols 40..63 zero) + base -> out
// ---------------------------------------------------------------------------
__global__ __launch_bounds__(256, 8) void k_gather2(
    const ushort_t* __restrict__ rows, const int* __restrict__ rowptr,
    const int* __restrict__ srcs, const float* __restrict__ base,
    float* __restrict__ out)
{
    const int lane = threadIdx.x & 63;
    const int w    = threadIdx.x >> 6;
    const int p    = lane & 7;
    const int gb   = lane & 56;
    const int node = blockIdx.x * 32 + w * 8 + (lane >> 3);

    const int beg = rowptr[node];
    const int nb  = rowptr[node + 1] - beg;

    float a0=0,a1=0,a2=0,a3=0,a4=0,a5=0,a6=0,a7=0;
    for (int j0 = 0; j0 < nb; j0 += 8) {
        const int cnt = min(nb - j0, 8);
        const int idx = (p < cnt) ? srcs[beg + j0 + p] : 0;
        int t = 0;
        for (; t + 3 < cnt; t += 4) {
            int s0 = __shfl(idx, gb + t),     s1 = __shfl(idx, gb + t + 1);
            int s2 = __shfl(idx, gb + t + 2), s3 = __shfl(idx, gb + t + 3);
            const uint4 v0 = *reinterpret_cast<const uint4*>(rows + (size_t)s0 * 64 + p * 8);
            const uint4 v1 = *reinterpret_cast<const uint4*>(rows + (size_t)s1 * 64 + p * 8);
            const uint4 v2 = *reinterpret_cast<const uint4*>(rows + (size_t)s2 * 64 + p * 8);
            const uint4 v3 = *reinterpret_cast<const uint4*>(rows + (size_t)s3 * 64 + p * 8);
            a0 += bflo(v0.x)+bflo(v1.x)+bflo(v2.x)+bflo(v3.x);
            a1 += bfhi(v0.x)+bfhi(v1.x)+bfhi(v2.x)+bfhi(v3.x);
            a2 += bflo(v0.y)+bflo(v1.y)+bflo(v2.y)+bflo(v3.y);
            a3 += bfhi(v0.y)+bfhi(v1.y)+bfhi(v2.y)+bfhi(v3.y);
            a4 += bflo(v0.z)+bflo(v1.z)+bflo(v2.z)+bflo(v3.z);
            a5 += bfhi(v0.z)+bfhi(v1.z)+bfhi(v2.z)+bfhi(v3.z);
            a6 += bflo(v0.w)+bflo(v1.w)+bflo(v2.w)+bflo(v3.w);
            a7 += bfhi(v0.w)+bfhi(v1.w)+bfhi(v2.w)+bfhi(v3.w);
        }
        for (; t < cnt; ++t) {
            int s = __shfl(idx, gb + t);
            const uint4 v = *reinterpret_cast<const uint4*>(rows + (size_t)s * 64 + p * 8);
            a0 += bflo(v.x); a1 += bfhi(v.x); a2 += bflo(v.y); a3 += bfhi(v.y);
            a4 += bflo(v.z); a5 += bfhi(v.z); a6 += bflo(v.w); a7 += bfhi(v.w);
        }
    }
    if (p < 5) {
        const float inv = 1.0f / (float)max(nb, 1);
        const float4 bb0 = *reinterpret_cast<const float4*>(base + (size_t)node * 40 + p * 8);
        const float4 bb1 = *reinterpret_cast<const float4*>(base + (size_t)node * 40 + p * 8 + 4);
        float4 r0, r1;
        r0.x = a0*inv + bb0.x; r0.y = a1*inv + bb0.y; r0.z = a2*inv + bb0.z; r0.w = a3*inv + bb0.w;
        r1.x = a4*inv + bb1.x; r1.y = a5*inv + bb1.y; r1.z = a6*inv + bb1.z; r1.w = a7*inv + bb1.w;
        *reinterpret_cast<float4*>(out + (size_t)node * 40 + p * 8)     = r0;
        *reinterpret_cast<float4*>(out + (size_t)node * 40 + p * 8 + 4) = r1;
    }
}

// ---------------------------------------------------------------------------
// Workspace (4-byte units unless noted):
//   [0, NN)            deg_i (int)
//   [NN, 2NN)          cursor (int)
//   [2NN, 3NN+8)       rowptr (int)
//   [3NN+8, +EE)       srcs (int)
//   [.., +NB]          bsum (int)     [.., +NB]  boff (int)
//   then bf16: xb (NN*64), aggm_b (NN*64), hW2b (NN*64); f32: base (NN*40)
//   Per call: zero deg_i+cursor (800KB) and hW2b (12.8MB).
// ---------------------------------------------------------------------------
extern "C" void kernel_launch(void* const* d_in, const int* in_sizes, int n_in,
                              void* d_out, int out_size, void* d_ws, size_t ws_size,
                              hipStream_t stream) {
    const float* x   = (const float*)d_in[0];
    const int*   ei  = (const int*)  d_in[1];
    const float* W1l = (const float*)d_in[2];
    const float* W1r = (const float*)d_in[3];
    const float* b1  = (const float*)d_in[4];
    const float* W2l = (const float*)d_in[5];
    const float* W2r = (const float*)d_in[6];
    const float* b2  = (const float*)d_in[7];
    float* out = (float*)d_out;

    int* wsi = (int*)d_ws;
    int* deg_i  = wsi;
    int* cursor = wsi + NN;
    int* rowptr = wsi + 2 * NN;
    int* srcs   = wsi + 3 * NN + 8;
    int* bsum   = srcs + EE;
    int* boff   = bsum + NB;
    ushort_t* xb     = (ushort_t*)(boff + NB + 4);
    ushort_t* aggm_b = xb     + (size_t)NN * 64;
    ushort_t* hW2b   = aggm_b + (size_t)NN * 64;
    float*    base   = (float*)(hW2b + (size_t)NN * 64);

    hipMemsetAsync(d_ws, 0, sizeof(int) * (size_t)2 * NN, stream);
    hipMemsetAsync(hW2b, 0, sizeof(ushort_t) * (size_t)NN * 64, stream);

    k_cast<<<NN * 64 / 8 / 256, 256, 0, stream>>>(x, xb);
    k_hist<<<(EE + 255) / 256, 256, 0, stream>>>(ei, deg_i);
    k_scanA<<<NB, 256, 0, stream>>>(deg_i, bsum);
    k_scanB<<<1, 128, 0, stream>>>(bsum, boff, rowptr);
    k_scanC<<<NB, 256, 0, stream>>>(deg_i, boff, rowptr);
    k_fill<<<(EE + 255) / 256, 256, 0, stream>>>(ei, rowptr, cursor, srcs);
    k_gather1<<<NN / 32, 256, 0, stream>>>(xb, rowptr, srcs, aggm_b);
    k_dense1<<<(NN + 63) / 64, 256, 0, stream>>>(xb, aggm_b, W1l, W1r, b1,
                                                 W2l, W2r, b2, hW2b, base);
    k_gather2<<<NN / 32, 256, 0, stream>>>(hW2b, rowptr, srcs, base, out);
}

// Round 7
// 195.750 us; speedup vs baseline: 9.7391x; 1.1305x over previous
//
#include <hip/hip_runtime.h>

#define NN 100000
#define EE 1000000
#define NB 98           // ceil(NN / 1024) scan blocks

typedef unsigned short ushort_t;
typedef short bf16x8 __attribute__((ext_vector_type(8)));
typedef float f32x4 __attribute__((ext_vector_type(4)));

// ---- bf16 helpers (RTNE pack, shift unpack) -------------------------------
__device__ __forceinline__ unsigned short f2bf(float f) {
    unsigned u = __builtin_bit_cast(unsigned, f);
    u += 0x7fffu + ((u >> 16) & 1u);
    return (unsigned short)(u >> 16);
}
__device__ __forceinline__ float bflo(unsigned u) {
    return __builtin_bit_cast(float, u << 16);
}
__device__ __forceinline__ float bfhi(unsigned u) {
    return __builtin_bit_cast(float, u & 0xffff0000u);
}
__device__ __forceinline__ unsigned pk2(float a, float b) {
    return (unsigned)f2bf(a) | ((unsigned)f2bf(b) << 16);
}

// ---------------------------------------------------------------------------
// K0: cast x (f32) -> xb (bf16).  8 elems/thread.
// ---------------------------------------------------------------------------
__global__ __launch_bounds__(256) void k_cast(
    const float* __restrict__ x, ushort_t* __restrict__ xb)
{
    size_t t = (size_t)blockIdx.x * 256 + threadIdx.x;
    const float4 v0 = *reinterpret_cast<const float4*>(x + t * 8);
    const float4 v1 = *reinterpret_cast<const float4*>(x + t * 8 + 4);
    uint4 r;
    r.x = pk2(v0.x, v0.y); r.y = pk2(v0.z, v0.w);
    r.z = pk2(v1.x, v1.y); r.w = pk2(v1.z, v1.w);
    *reinterpret_cast<uint4*>(xb + t * 8) = r;
}

// ---------------------------------------------------------------------------
// K1: histogram of dst -> deg_i.  4 edges/thread (int4) -> 4 atomics in flight.
// ---------------------------------------------------------------------------
__global__ __launch_bounds__(256) void k_hist(
    const int* __restrict__ ei, int* __restrict__ deg_i)
{
    const int e0 = (blockIdx.x * 256 + threadIdx.x) * 4;
    if (e0 >= EE) return;
    const int4 d = *reinterpret_cast<const int4*>(ei + EE + e0);
    atomicAdd(deg_i + d.x, 1);
    atomicAdd(deg_i + d.y, 1);
    atomicAdd(deg_i + d.z, 1);
    atomicAdd(deg_i + d.w, 1);
}

// ---------------------------------------------------------------------------
// K2a: per-block (1024-int chunk) sum -> bsum[b]
// ---------------------------------------------------------------------------
__global__ __launch_bounds__(256) void k_scanA(
    const int* __restrict__ deg_i, int* __restrict__ bsum)
{
    const int b = blockIdx.x, t = threadIdx.x;
    const int i = b * 1024 + t * 4;
    int s = 0;
    if (i + 3 < NN) {
        const int4 v = *reinterpret_cast<const int4*>(deg_i + i);
        s = v.x + v.y + v.z + v.w;
    } else {
        for (int j = 0; j < 4; ++j) if (i + j < NN) s += deg_i[i + j];
    }
    #pragma unroll
    for (int off = 32; off; off >>= 1) s += __shfl_down(s, off);
    __shared__ int red[4];
    if ((t & 63) == 0) red[t >> 6] = s;
    __syncthreads();
    if (t == 0) bsum[b] = red[0] + red[1] + red[2] + red[3];
}

// ---------------------------------------------------------------------------
// K2b: exclusive scan of bsum[NB] -> boff[NB]; rowptr[NN] = total (== EE)
// ---------------------------------------------------------------------------
__global__ __launch_bounds__(128) void k_scanB(
    const int* __restrict__ bsum, int* __restrict__ boff, int* __restrict__ rowptr)
{
    __shared__ int part[128];
    const int t = threadIdx.x;
    const int v = (t < NB) ? bsum[t] : 0;
    part[t] = v;
    __syncthreads();
    for (int off = 1; off < 128; off <<= 1) {
        int u = (t >= off) ? part[t - off] : 0;
        __syncthreads();
        part[t] += u;
        __syncthreads();
    }
    if (t < NB) boff[t] = part[t] - v;
    if (t == 127) rowptr[NN] = part[127];
}

// ---------------------------------------------------------------------------
// K2c: block-local exclusive scan + boff[b] -> rowptr AND cursor (cursor
// starts at rowptr so k_fill's atomic needs no separate rowptr load).
// ---------------------------------------------------------------------------
__global__ __launch_bounds__(256) void k_scanC(
    const int* __restrict__ deg_i, const int* __restrict__ boff,
    int* __restrict__ rowptr, int* __restrict__ cursor)
{
    const int b = blockIdx.x, t = threadIdx.x;
    const int i = b * 1024 + t * 4;
    int e0 = 0, e1 = 0, e2 = 0, e3 = 0;
    if (i + 3 < NN) {
        const int4 v = *reinterpret_cast<const int4*>(deg_i + i);
        e0 = v.x; e1 = v.y; e2 = v.z; e3 = v.w;
    } else {
        if (i     < NN) e0 = deg_i[i];
        if (i + 1 < NN) e1 = deg_i[i + 1];
        if (i + 2 < NN) e2 = deg_i[i + 2];
        if (i + 3 < NN) e3 = deg_i[i + 3];
    }
    const int s = e0 + e1 + e2 + e3;
    __shared__ int part[256];
    part[t] = s;
    __syncthreads();
    for (int off = 1; off < 256; off <<= 1) {
        int u = (t >= off) ? part[t - off] : 0;
        __syncthreads();
        part[t] += u;
        __syncthreads();
    }
    const int excl = part[t] - s + boff[b];
    const int r0 = excl, r1 = excl + e0, r2 = excl + e0 + e1, r3 = excl + e0 + e1 + e2;
    if (i     < NN) { rowptr[i]     = r0; cursor[i]     = r0; }
    if (i + 1 < NN) { rowptr[i + 1] = r1; cursor[i + 1] = r1; }
    if (i + 2 < NN) { rowptr[i + 2] = r2; cursor[i + 2] = r2; }
    if (i + 3 < NN) { rowptr[i + 3] = r3; cursor[i + 3] = r3; }
}

// ---------------------------------------------------------------------------
// K3: bucket fill.  4 edges/thread; srcs written with agent-scope stores so
// lines merge once at the memory-side cache (no per-XCD dirty-line ping-pong).
// ---------------------------------------------------------------------------
__global__ __launch_bounds__(256) void k_fill(
    const int* __restrict__ ei, int* __restrict__ cursor, int* __restrict__ srcs)
{
    const int e0 = (blockIdx.x * 256 + threadIdx.x) * 4;
    if (e0 >= EE) return;
    const int4 d = *reinterpret_cast<const int4*>(ei + EE + e0);
    const int4 s = *reinterpret_cast<const int4*>(ei + e0);
    const int p0 = atomicAdd(cursor + d.x, 1);
    const int p1 = atomicAdd(cursor + d.y, 1);
    const int p2 = atomicAdd(cursor + d.z, 1);
    const int p3 = atomicAdd(cursor + d.w, 1);
    __hip_atomic_store(srcs + p0, s.x, __ATOMIC_RELAXED, __HIP_MEMORY_SCOPE_AGENT);
    __hip_atomic_store(srcs + p1, s.y, __ATOMIC_RELAXED, __HIP_MEMORY_SCOPE_AGENT);
    __hip_atomic_store(srcs + p2, s.z, __ATOMIC_RELAXED, __HIP_MEMORY_SCOPE_AGENT);
    __hip_atomic_store(srcs + p3, s.w, __ATOMIC_RELAXED, __HIP_MEMORY_SCOPE_AGENT);
}

// ---------------------------------------------------------------------------
// K4: gather-mean over bf16 stride-64 rows (128B/row).  8 lanes/node x 16B,
// 8 nodes/wave, 32 nodes/block, no LDS, 4-way unrolled.  Output bf16 mean.
// ---------------------------------------------------------------------------
__global__ __launch_bounds__(256, 8) void k_gather1(
    const ushort_t* __restrict__ rows, const int* __restrict__ rowptr,
    const int* __restrict__ srcs, ushort_t* __restrict__ aggm)
{
    const int lane = threadIdx.x & 63;
    const int w    = threadIdx.x >> 6;
    const int p    = lane & 7;
    const int gb   = lane & 56;
    const int node = blockIdx.x * 32 + w * 8 + (lane >> 3);

    const int beg = rowptr[node];
    const int nb  = rowptr[node + 1] - beg;

    float a0=0,a1=0,a2=0,a3=0,a4=0,a5=0,a6=0,a7=0;
    for (int j0 = 0; j0 < nb; j0 += 8) {
        const int cnt = min(nb - j0, 8);
        const int idx = (p < cnt) ? srcs[beg + j0 + p] : 0;
        int t = 0;
        for (; t + 3 < cnt; t += 4) {
            int s0 = __shfl(idx, gb + t),     s1 = __shfl(idx, gb + t + 1);
            int s2 = __shfl(idx, gb + t + 2), s3 = __shfl(idx, gb + t + 3);
            const uint4 v0 = *reinterpret_cast<const uint4*>(rows + (size_t)s0 * 64 + p * 8);
            const uint4 v1 = *reinterpret_cast<const uint4*>(rows + (size_t)s1 * 64 + p * 8);
            const uint4 v2 = *reinterpret_cast<const uint4*>(rows + (size_t)s2 * 64 + p * 8);
            const uint4 v3 = *reinterpret_cast<const uint4*>(rows + (size_t)s3 * 64 + p * 8);
            a0 += bflo(v0.x)+bflo(v1.x)+bflo(v2.x)+bflo(v3.x);
            a1 += bfhi(v0.x)+bfhi(v1.x)+bfhi(v2.x)+bfhi(v3.x);
            a2 += bflo(v0.y)+bflo(v1.y)+bflo(v2.y)+bflo(v3.y);
            a3 += bfhi(v0.y)+bfhi(v1.y)+bfhi(v2.y)+bfhi(v3.y);
            a4 += bflo(v0.z)+bflo(v1.z)+bflo(v2.z)+bflo(v3.z);
            a5 += bfhi(v0.z)+bfhi(v1.z)+bfhi(v2.z)+bfhi(v3.z);
            a6 += bflo(v0.w)+bflo(v1.w)+bflo(v2.w)+bflo(v3.w);
            a7 += bfhi(v0.w)+bfhi(v1.w)+bfhi(v2.w)+bfhi(v3.w);
        }
        for (; t < cnt; ++t) {
            int s = __shfl(idx, gb + t);
            const uint4 v = *reinterpret_cast<const uint4*>(rows + (size_t)s * 64 + p * 8);
            a0 += bflo(v.x); a1 += bfhi(v.x); a2 += bflo(v.y); a3 += bfhi(v.y);
            a4 += bflo(v.z); a5 += bfhi(v.z); a6 += bflo(v.w); a7 += bfhi(v.w);
        }
    }
    const float inv = 1.0f / (float)max(nb, 1);
    uint4 r;
    r.x = pk2(a0*inv, a1*inv); r.y = pk2(a2*inv, a3*inv);
    r.z = pk2(a4*inv, a5*inv); r.w = pk2(a6*inv, a7*inv);
    *reinterpret_cast<uint4*>(aggm + (size_t)node * 64 + p * 8) = r;
}

// ---------------------------------------------------------------------------
// K5: MFMA dense layer.  256 thr = 4 waves; wave owns 16 nodes.
//   GEMM1: [aggm_b | xb] (16x128) @ W1cat (128x64) -> relu -> h (bf16 LDS)
//   GEMM2: h (16x64) @ [W2l | W2r] (64x80)
//     f2 in  0..39  -> hW2b[f2] = bf16(v);  f2 in 40..63 -> hW2b[f2] = 0
//     f2 in 40..79  -> base[f2-40] = v + b2[f2-40]   (nt = 2,3,4!)
// ---------------------------------------------------------------------------
__global__ __launch_bounds__(256) void k_dense1(
    const ushort_t* __restrict__ xb, const ushort_t* __restrict__ aggm_b,
    const float* __restrict__ W1l, const float* __restrict__ W1r,
    const float* __restrict__ b1,  const float* __restrict__ W2l,
    const float* __restrict__ W2r, const float* __restrict__ b2,
    ushort_t* __restrict__ hW2b, float* __restrict__ base)
{
    __shared__ __align__(16) ushort_t sW1T[64 * 136];
    __shared__ __align__(16) ushort_t sW2T[80 * 72];
    __shared__ __align__(16) ushort_t sH[4][16 * 72];
    __shared__ float sB1[64];
    __shared__ float sB2[40];

    const int t = threadIdx.x;
    {
        const int n = t & 63, kr = t >> 6;
        for (int i = 0; i < 32; ++i) {
            int k = kr * 32 + i;
            float v = (k < 64) ? W1l[k * 64 + n] : W1r[(k - 64) * 64 + n];
            sW1T[n * 136 + k] = f2bf(v);
        }
    }
    for (int idx = t; idx < 80 * 64; idx += 256) {
        int n2 = idx % 80, k = idx / 80;
        float v = (n2 < 40) ? W2l[k * 40 + n2] : W2r[k * 40 + (n2 - 40)];
        sW2T[n2 * 72 + k] = f2bf(v);
    }
    if (t < 64) sB1[t] = b1[t];
    if (t < 40) sB2[t] = b2[t];
    __syncthreads();

    const int w = t >> 6, lane = t & 63;
    const int l15 = lane & 15, g = lane >> 4;
    const int nbase = blockIdx.x * 64 + w * 16;
    const int arow = min(nbase + l15, NN - 1);

    const f32x4 zero = {0.f, 0.f, 0.f, 0.f};
    f32x4 acc0 = zero, acc1 = zero, acc2_ = zero, acc3 = zero;
    bf16x8 afr[4];
    #pragma unroll
    for (int ks = 0; ks < 4; ++ks) {
        const int k0 = ks * 32;
        const ushort_t* src = (k0 < 64)
            ? (aggm_b + (size_t)arow * 64 + k0 + 8 * g)
            : (xb     + (size_t)arow * 64 + (k0 - 64) + 8 * g);
        afr[ks] = *reinterpret_cast<const bf16x8*>(src);
    }
    #pragma unroll
    for (int ks = 0; ks < 4; ++ks) {
        const bf16x8 b0  = *reinterpret_cast<const bf16x8*>(&sW1T[( 0 + l15) * 136 + ks * 32 + 8 * g]);
        const bf16x8 b1f = *reinterpret_cast<const bf16x8*>(&sW1T[(16 + l15) * 136 + ks * 32 + 8 * g]);
        const bf16x8 b2f = *reinterpret_cast<const bf16x8*>(&sW1T[(32 + l15) * 136 + ks * 32 + 8 * g]);
        const bf16x8 b3f = *reinterpret_cast<const bf16x8*>(&sW1T[(48 + l15) * 136 + ks * 32 + 8 * g]);
        acc0  = __builtin_amdgcn_mfma_f32_16x16x32_bf16(afr[ks], b0,  acc0,  0, 0, 0);
        acc1  = __builtin_amdgcn_mfma_f32_16x16x32_bf16(afr[ks], b1f, acc1,  0, 0, 0);
        acc2_ = __builtin_amdgcn_mfma_f32_16x16x32_bf16(afr[ks], b2f, acc2_, 0, 0, 0);
        acc3  = __builtin_amdgcn_mfma_f32_16x16x32_bf16(afr[ks], b3f, acc3,  0, 0, 0);
    }

    {
        const float bb0 = sB1[ 0 + l15], bb1 = sB1[16 + l15];
        const float bb2 = sB1[32 + l15], bb3 = sB1[48 + l15];
        #pragma unroll
        for (int r = 0; r < 4; ++r) {
            const int row = g * 4 + r;
            sH[w][row * 72 +  0 + l15] = f2bf(fmaxf(acc0[r]  + bb0, 0.f));
            sH[w][row * 72 + 16 + l15] = f2bf(fmaxf(acc1[r]  + bb1, 0.f));
            sH[w][row * 72 + 32 + l15] = f2bf(fmaxf(acc2_[r] + bb2, 0.f));
            sH[w][row * 72 + 48 + l15] = f2bf(fmaxf(acc3[r]  + bb3, 0.f));
        }
    }
    __syncthreads();

    bf16x8 a2[2];
    a2[0] = *reinterpret_cast<const bf16x8*>(&sH[w][l15 * 72 +  0 + 8 * g]);
    a2[1] = *reinterpret_cast<const bf16x8*>(&sH[w][l15 * 72 + 32 + 8 * g]);
    f32x4 o[5] = {zero, zero, zero, zero, zero};
    #pragma unroll
    for (int nt = 0; nt < 5; ++nt) {
        #pragma unroll
        for (int ks = 0; ks < 2; ++ks) {
            const bf16x8 bfr = *reinterpret_cast<const bf16x8*>(
                &sW2T[(nt * 16 + l15) * 72 + ks * 32 + 8 * g]);
            o[nt] = __builtin_amdgcn_mfma_f32_16x16x32_bf16(a2[ks], bfr, o[nt], 0, 0, 0);
        }
    }

    #pragma unroll
    for (int nt = 0; nt < 5; ++nt) {
        const int f2 = nt * 16 + l15;
        #pragma unroll
        for (int r = 0; r < 4; ++r) {
            const int node = nbase + g * 4 + r;
            if (node < NN) {
                const float v = o[nt][r];
                if (f2 < 64)   // cols 0..39 = h@W2l, cols 40..63 = 0 padding
                    hW2b[(size_t)node * 64 + f2] = (f2 < 40) ? f2bf(v) : (ushort_t)0;
                if (f2 >= 40)  // feats 40..79 -> base (spans nt = 2, 3, 4)
                    base[(size_t)node * 40 + (f2 - 40)] = v + sB2[f2 - 40];
            }
        }
    }
}

// ---------------------------------------------------------------------------
// K6: gather-mean over hW2b (bf16 stride-64, cols 40..63 zero) + base -> out
// ---------------------------------------------------------------------------
__global__ __launch_bounds__(256, 8) void k_gather2(
    const ushort_t* __restrict__ rows, const int* __restrict__ rowptr,
    const int* __restrict__ srcs, const float* __restrict__ base,
    float* __restrict__ out)
{
    const int lane = threadIdx.x & 63;
    const int w    = threadIdx.x >> 6;
    const int p    = lane & 7;
    const int gb   = lane & 56;
    const int node = blockIdx.x * 32 + w * 8 + (lane >> 3);

    const int beg = rowptr[node];
    const int nb  = rowptr[node + 1] - beg;

    float a0=0,a1=0,a2=0,a3=0,a4=0,a5=0,a6=0,a7=0;
    for (int j0 = 0; j0 < nb; j0 += 8) {
        const int cnt = min(nb - j0, 8);
        const int idx = (p < cnt) ? srcs[beg + j0 + p] : 0;
        int t = 0;
        for (; t + 3 < cnt; t += 4) {
            int s0 = __shfl(idx, gb + t),     s1 = __shfl(idx, gb + t + 1);
            int s2 = __shfl(idx, gb + t + 2), s3 = __shfl(idx, gb + t + 3);
            const uint4 v0 = *reinterpret_cast<const uint4*>(rows + (size_t)s0 * 64 + p * 8);
            const uint4 v1 = *reinterpret_cast<const uint4*>(rows + (size_t)s1 * 64 + p * 8);
            const uint4 v2 = *reinterpret_cast<const uint4*>(rows + (size_t)s2 * 64 + p * 8);
            const uint4 v3 = *reinterpret_cast<const uint4*>(rows + (size_t)s3 * 64 + p * 8);
            a0 += bflo(v0.x)+bflo(v1.x)+bflo(v2.x)+bflo(v3.x);
            a1 += bfhi(v0.x)+bfhi(v1.x)+bfhi(v2.x)+bfhi(v3.x);
            a2 += bflo(v0.y)+bflo(v1.y)+bflo(v2.y)+bflo(v3.y);
            a3 += bfhi(v0.y)+bfhi(v1.y)+bfhi(v2.y)+bfhi(v3.y);
            a4 += bflo(v0.z)+bflo(v1.z)+bflo(v2.z)+bflo(v3.z);
            a5 += bfhi(v0.z)+bfhi(v1.z)+bfhi(v2.z)+bfhi(v3.z);
            a6 += bflo(v0.w)+bflo(v1.w)+bflo(v2.w)+bflo(v3.w);
            a7 += bfhi(v0.w)+bfhi(v1.w)+bfhi(v2.w)+bfhi(v3.w);
        }
        for (; t < cnt; ++t) {
            int s = __shfl(idx, gb + t);
            const uint4 v = *reinterpret_cast<const uint4*>(rows + (size_t)s * 64 + p * 8);
            a0 += bflo(v.x); a1 += bfhi(v.x); a2 += bflo(v.y); a3 += bfhi(v.y);
            a4 += bflo(v.z); a5 += bfhi(v.z); a6 += bflo(v.w); a7 += bfhi(v.w);
        }
    }
    if (p < 5) {
        const float inv = 1.0f / (float)max(nb, 1);
        const float4 bb0 = *reinterpret_cast<const float4*>(base + (size_t)node * 40 + p * 8);
        const float4 bb1 = *reinterpret_cast<const float4*>(base + (size_t)node * 40 + p * 8 + 4);
        float4 r0, r1;
        r0.x = a0*inv + bb0.x; r0.y = a1*inv + bb0.y; r0.z = a2*inv + bb0.z; r0.w = a3*inv + bb0.w;
        r1.x = a4*inv + bb1.x; r1.y = a5*inv + bb1.y; r1.z = a6*inv + bb1.z; r1.w = a7*inv + bb1.w;
        *reinterpret_cast<float4*>(out + (size_t)node * 40 + p * 8)     = r0;
        *reinterpret_cast<float4*>(out + (size_t)node * 40 + p * 8 + 4) = r1;
    }
}

// ---------------------------------------------------------------------------
// Workspace (4-byte units unless noted):
//   [0, NN)            deg_i (int)         <- memset each call
//   [NN, 2NN)          cursor (int)        <- written by scanC
//   [2NN, 3NN+8)       rowptr (int)
//   [3NN+8, +EE)       srcs (int)
//   [.., +NB]          bsum   [.., +NB]  boff
//   then bf16: xb (NN*64), aggm_b (NN*64), hW2b (NN*64); f32: base (NN*40)
// ---------------------------------------------------------------------------
extern "C" void kernel_launch(void* const* d_in, const int* in_sizes, int n_in,
                              void* d_out, int out_size, void* d_ws, size_t ws_size,
                              hipStream_t stream) {
    const float* x   = (const float*)d_in[0];
    const int*   ei  = (const int*)  d_in[1];
    const float* W1l = (const float*)d_in[2];
    const float* W1r = (const float*)d_in[3];
    const float* b1  = (const float*)d_in[4];
    const float* W2l = (const float*)d_in[5];
    const float* W2r = (const float*)d_in[6];
    const float* b2  = (const float*)d_in[7];
    float* out = (float*)d_out;

    int* wsi = (int*)d_ws;
    int* deg_i  = wsi;
    int* cursor = wsi + NN;
    int* rowptr = wsi + 2 * NN;
    int* srcs   = wsi + 3 * NN + 8;
    int* bsum   = srcs + EE;
    int* boff   = bsum + NB;
    ushort_t* xb     = (ushort_t*)(boff + NB + 4);
    ushort_t* aggm_b = xb     + (size_t)NN * 64;
    ushort_t* hW2b   = aggm_b + (size_t)NN * 64;
    float*    base   = (float*)(hW2b + (size_t)NN * 64);

    hipMemsetAsync(deg_i, 0, sizeof(int) * (size_t)NN, stream);

    k_cast<<<NN * 64 / 8 / 256, 256, 0, stream>>>(x, xb);
    k_hist<<<(EE / 4 + 255) / 256, 256, 0, stream>>>(ei, deg_i);
    k_scanA<<<NB, 256, 0, stream>>>(deg_i, bsum);
    k_scanB<<<1, 128, 0, stream>>>(bsum, boff, rowptr);
    k_scanC<<<NB, 256, 0, stream>>>(deg_i, boff, rowptr, cursor);
    k_fill<<<(EE / 4 + 255) / 256, 256, 0, stream>>>(ei, cursor, srcs);
    k_gather1<<<NN / 32, 256, 0, stream>>>(xb, rowptr, srcs, aggm_b);
    k_dense1<<<(NN + 63) / 64, 256, 0, stream>>>(xb, aggm_b, W1l, W1r, b1,
                                                 W2l, W2r, b2, hW2b, base);
    k_gather2<<<NN / 32, 256, 0, stream>>>(hW2b, rowptr, srcs, base, out);
}

// Round 8
// 195.305 us; speedup vs baseline: 9.7613x; 1.0023x over previous
//
#include <hip/hip_runtime.h>

#define NN 100000
#define EE 1000000
#define NB 98           // ceil(NN / 1024) scan blocks
#define NXCD 8
#define FCH 256         // fill edge-chunks; grid = FCH * NXCD
#define FCHSZ ((EE + FCH - 1) / FCH)   // 3907 edges per chunk

typedef unsigned short ushort_t;
typedef short bf16x8 __attribute__((ext_vector_type(8)));
typedef float f32x4 __attribute__((ext_vector_type(4)));

// ---- bf16 helpers (RTNE pack, shift unpack) -------------------------------
__device__ __forceinline__ unsigned short f2bf(float f) {
    unsigned u = __builtin_bit_cast(unsigned, f);
    u += 0x7fffu + ((u >> 16) & 1u);
    return (unsigned short)(u >> 16);
}
__device__ __forceinline__ float bflo(unsigned u) {
    return __builtin_bit_cast(float, u << 16);
}
__device__ __forceinline__ float bfhi(unsigned u) {
    return __builtin_bit_cast(float, u & 0xffff0000u);
}
__device__ __forceinline__ unsigned pk2(float a, float b) {
    return (unsigned)f2bf(a) | ((unsigned)f2bf(b) << 16);
}

// ---------------------------------------------------------------------------
// K0: cast x (f32) -> xb (bf16).  8 elems/thread.
// ---------------------------------------------------------------------------
__global__ __launch_bounds__(256) void k_cast(
    const float* __restrict__ x, ushort_t* __restrict__ xb)
{
    size_t t = (size_t)blockIdx.x * 256 + threadIdx.x;
    const float4 v0 = *reinterpret_cast<const float4*>(x + t * 8);
    const float4 v1 = *reinterpret_cast<const float4*>(x + t * 8 + 4);
    uint4 r;
    r.x = pk2(v0.x, v0.y); r.y = pk2(v0.z, v0.w);
    r.z = pk2(v1.x, v1.y); r.w = pk2(v1.z, v1.w);
    *reinterpret_cast<uint4*>(xb + t * 8) = r;
}

// ---------------------------------------------------------------------------
// K1: histogram of dst -> deg_i.  4 edges/thread (int4) -> 4 atomics in flight.
// ---------------------------------------------------------------------------
__global__ __launch_bounds__(256) void k_hist(
    const int* __restrict__ ei, int* __restrict__ deg_i)
{
    const int e0 = (blockIdx.x * 256 + threadIdx.x) * 4;
    if (e0 >= EE) return;
    const int4 d = *reinterpret_cast<const int4*>(ei + EE + e0);
    atomicAdd(deg_i + d.x, 1);
    atomicAdd(deg_i + d.y, 1);
    atomicAdd(deg_i + d.z, 1);
    atomicAdd(deg_i + d.w, 1);
}

// ---------------------------------------------------------------------------
// K2a: per-block (1024-int chunk) sum -> bsum[b]
// ---------------------------------------------------------------------------
__global__ __launch_bounds__(256) void k_scanA(
    const int* __restrict__ deg_i, int* __restrict__ bsum)
{
    const int b = blockIdx.x, t = threadIdx.x;
    const int i = b * 1024 + t * 4;
    int s = 0;
    if (i + 3 < NN) {
        const int4 v = *reinterpret_cast<const int4*>(deg_i + i);
        s = v.x + v.y + v.z + v.w;
    } else {
        for (int j = 0; j < 4; ++j) if (i + j < NN) s += deg_i[i + j];
    }
    #pragma unroll
    for (int off = 32; off; off >>= 1) s += __shfl_down(s, off);
    __shared__ int red[4];
    if ((t & 63) == 0) red[t >> 6] = s;
    __syncthreads();
    if (t == 0) bsum[b] = red[0] + red[1] + red[2] + red[3];
}

// ---------------------------------------------------------------------------
// K2b: exclusive scan of bsum[NB] -> boff[NB]; rowptr[NN] = total (== EE)
// ---------------------------------------------------------------------------
__global__ __launch_bounds__(128) void k_scanB(
    const int* __restrict__ bsum, int* __restrict__ boff, int* __restrict__ rowptr)
{
    __shared__ int part[128];
    const int t = threadIdx.x;
    const int v = (t < NB) ? bsum[t] : 0;
    part[t] = v;
    __syncthreads();
    for (int off = 1; off < 128; off <<= 1) {
        int u = (t >= off) ? part[t - off] : 0;
        __syncthreads();
        part[t] += u;
        __syncthreads();
    }
    if (t < NB) boff[t] = part[t] - v;
    if (t == 127) rowptr[NN] = part[127];
}

// ---------------------------------------------------------------------------
// K2c: block-local exclusive scan + boff[b] -> rowptr AND cursor (cursor
// starts at rowptr so k_fill's atomic needs no separate rowptr load).
// ---------------------------------------------------------------------------
__global__ __launch_bounds__(256) void k_scanC(
    const int* __restrict__ deg_i, const int* __restrict__ boff,
    int* __restrict__ rowptr, int* __restrict__ cursor)
{
    const int b = blockIdx.x, t = threadIdx.x;
    const int i = b * 1024 + t * 4;
    int e0 = 0, e1 = 0, e2 = 0, e3 = 0;
    if (i + 3 < NN) {
        const int4 v = *reinterpret_cast<const int4*>(deg_i + i);
        e0 = v.x; e1 = v.y; e2 = v.z; e3 = v.w;
    } else {
        if (i     < NN) e0 = deg_i[i];
        if (i + 1 < NN) e1 = deg_i[i + 1];
        if (i + 2 < NN) e2 = deg_i[i + 2];
        if (i + 3 < NN) e3 = deg_i[i + 3];
    }
    const int s = e0 + e1 + e2 + e3;
    __shared__ int part[256];
    part[t] = s;
    __syncthreads();
    for (int off = 1; off < 256; off <<= 1) {
        int u = (t >= off) ? part[t - off] : 0;
        __syncthreads();
        part[t] += u;
        __syncthreads();
    }
    const int excl = part[t] - s + boff[b];
    const int r0 = excl, r1 = excl + e0, r2 = excl + e0 + e1, r3 = excl + e0 + e1 + e2;
    if (i     < NN) { rowptr[i]     = r0; cursor[i]     = r0; }
    if (i + 1 < NN) { rowptr[i + 1] = r1; cursor[i + 1] = r1; }
    if (i + 2 < NN) { rowptr[i + 2] = r2; cursor[i + 2] = r2; }
    if (i + 3 < NN) { rowptr[i + 3] = r3; cursor[i + 3] = r3; }
}

// ---------------------------------------------------------------------------
// K3: XCD-partitioned bucket fill.  Block b scans edge chunk (b>>3) and keeps
// only edges whose dst lies in range (b&7) of 8 contiguous dst ranges.  With
// blockIdx%8 ~ XCD id (dispatch round-robin), each srcs segment (~500KB) is
// written by ONE XCD -> its L2 merges scattered 4B stores into full lines.
// Correct regardless of the actual block->XCD mapping (each edge processed
// exactly once); the mapping only affects speed.
// ---------------------------------------------------------------------------
__global__ __launch_bounds__(256) void k_fill(
    const int* __restrict__ ei, int* __restrict__ cursor, int* __restrict__ srcs)
{
    const int rng   = blockIdx.x & (NXCD - 1);
    const int chunk = blockIdx.x >> 3;
    const int lo = rng * (NN / NXCD);          // 12500-node ranges (8*12500=NN)
    const int hi = lo + (NN / NXCD);
    const int ebeg = chunk * FCHSZ;
    const int eend = min(ebeg + FCHSZ, EE);
    for (int e = ebeg + threadIdx.x; e < eend; e += 256) {
        const int dst = ei[EE + e];
        if (dst >= lo && dst < hi) {
            const int pos = atomicAdd(cursor + dst, 1);
            srcs[pos] = ei[e];
        }
    }
}

// ---------------------------------------------------------------------------
// K4: gather-mean over bf16 stride-64 rows (128B/row).  8 lanes/node x 16B,
// 8 nodes/wave, 32 nodes/block, no LDS, 4-way unrolled.  Output bf16 mean.
// ---------------------------------------------------------------------------
__global__ __launch_bounds__(256, 8) void k_gather1(
    const ushort_t* __restrict__ rows, const int* __restrict__ rowptr,
    const int* __restrict__ srcs, ushort_t* __restrict__ aggm)
{
    const int lane = threadIdx.x & 63;
    const int w    = threadIdx.x >> 6;
    const int p    = lane & 7;
    const int gb   = lane & 56;
    const int node = blockIdx.x * 32 + w * 8 + (lane >> 3);

    const int beg = rowptr[node];
    const int nb  = rowptr[node + 1] - beg;

    float a0=0,a1=0,a2=0,a3=0,a4=0,a5=0,a6=0,a7=0;
    for (int j0 = 0; j0 < nb; j0 += 8) {
        const int cnt = min(nb - j0, 8);
        const int idx = (p < cnt) ? srcs[beg + j0 + p] : 0;
        int t = 0;
        for (; t + 3 < cnt; t += 4) {
            int s0 = __shfl(idx, gb + t),     s1 = __shfl(idx, gb + t + 1);
            int s2 = __shfl(idx, gb + t + 2), s3 = __shfl(idx, gb + t + 3);
            const uint4 v0 = *reinterpret_cast<const uint4*>(rows + (size_t)s0 * 64 + p * 8);
            const uint4 v1 = *reinterpret_cast<const uint4*>(rows + (size_t)s1 * 64 + p * 8);
            const uint4 v2 = *reinterpret_cast<const uint4*>(rows + (size_t)s2 * 64 + p * 8);
            const uint4 v3 = *reinterpret_cast<const uint4*>(rows + (size_t)s3 * 64 + p * 8);
            a0 += bflo(v0.x)+bflo(v1.x)+bflo(v2.x)+bflo(v3.x);
            a1 += bfhi(v0.x)+bfhi(v1.x)+bfhi(v2.x)+bfhi(v3.x);
            a2 += bflo(v0.y)+bflo(v1.y)+bflo(v2.y)+bflo(v3.y);
            a3 += bfhi(v0.y)+bfhi(v1.y)+bfhi(v2.y)+bfhi(v3.y);
            a4 += bflo(v0.z)+bflo(v1.z)+bflo(v2.z)+bflo(v3.z);
            a5 += bfhi(v0.z)+bfhi(v1.z)+bfhi(v2.z)+bfhi(v3.z);
            a6 += bflo(v0.w)+bflo(v1.w)+bflo(v2.w)+bflo(v3.w);
            a7 += bfhi(v0.w)+bfhi(v1.w)+bfhi(v2.w)+bfhi(v3.w);
        }
        for (; t < cnt; ++t) {
            int s = __shfl(idx, gb + t);
            const uint4 v = *reinterpret_cast<const uint4*>(rows + (size_t)s * 64 + p * 8);
            a0 += bflo(v.x); a1 += bfhi(v.x); a2 += bflo(v.y); a3 += bfhi(v.y);
            a4 += bflo(v.z); a5 += bfhi(v.z); a6 += bflo(v.w); a7 += bfhi(v.w);
        }
    }
    const float inv = 1.0f / (float)max(nb, 1);
    uint4 r;
    r.x = pk2(a0*inv, a1*inv); r.y = pk2(a2*inv, a3*inv);
    r.z = pk2(a4*inv, a5*inv); r.w = pk2(a6*inv, a7*inv);
    *reinterpret_cast<uint4*>(aggm + (size_t)node * 64 + p * 8) = r;
}

// ---------------------------------------------------------------------------
// K5: MFMA dense layer.  256 thr = 4 waves; wave owns 16 nodes.
//   GEMM1: [aggm_b | xb] (16x128) @ W1cat (128x64) -> relu -> h (bf16 LDS)
//   GEMM2: h (16x64) @ [W2l | W2r] (64x80)
//     f2 in  0..39  -> hW2b[f2] = bf16(v);  f2 in 40..63 -> hW2b[f2] = 0
//     f2 in 40..79  -> base[f2-40] = v + b2[f2-40]   (nt = 2,3,4!)
// ---------------------------------------------------------------------------
__global__ __launch_bounds__(256) void k_dense1(
    const ushort_t* __restrict__ xb, const ushort_t* __restrict__ aggm_b,
    const float* __restrict__ W1l, const float* __restrict__ W1r,
    const float* __restrict__ b1,  const float* __restrict__ W2l,
    const float* __restrict__ W2r, const float* __restrict__ b2,
    ushort_t* __restrict__ hW2b, float* __restrict__ base)
{
    __shared__ __align__(16) ushort_t sW1T[64 * 136];
    __shared__ __align__(16) ushort_t sW2T[80 * 72];
    __shared__ __align__(16) ushort_t sH[4][16 * 72];
    __shared__ float sB1[64];
    __shared__ float sB2[40];

    const int t = threadIdx.x;
    {
        const int n = t & 63, kr = t >> 6;
        for (int i = 0; i < 32; ++i) {
            int k = kr * 32 + i;
            float v = (k < 64) ? W1l[k * 64 + n] : W1r[(k - 64) * 64 + n];
            sW1T[n * 136 + k] = f2bf(v);
        }
    }
    for (int idx = t; idx < 80 * 64; idx += 256) {
        int n2 = idx % 80, k = idx / 80;
        float v = (n2 < 40) ? W2l[k * 40 + n2] : W2r[k * 40 + (n2 - 40)];
        sW2T[n2 * 72 + k] = f2bf(v);
    }
    if (t < 64) sB1[t] = b1[t];
    if (t < 40) sB2[t] = b2[t];
    __syncthreads();

    const int w = t >> 6, lane = t & 63;
    const int l15 = lane & 15, g = lane >> 4;
    const int nbase = blockIdx.x * 64 + w * 16;
    const int arow = min(nbase + l15, NN - 1);

    const f32x4 zero = {0.f, 0.f, 0.f, 0.f};
    f32x4 acc0 = zero, acc1 = zero, acc2_ = zero, acc3 = zero;
    bf16x8 afr[4];
    #pragma unroll
    for (int ks = 0; ks < 4; ++ks) {
        const int k0 = ks * 32;
        const ushort_t* src = (k0 < 64)
            ? (aggm_b + (size_t)arow * 64 + k0 + 8 * g)
            : (xb     + (size_t)arow * 64 + (k0 - 64) + 8 * g);
        afr[ks] = *reinterpret_cast<const bf16x8*>(src);
    }
    #pragma unroll
    for (int ks = 0; ks < 4; ++ks) {
        const bf16x8 b0  = *reinterpret_cast<const bf16x8*>(&sW1T[( 0 + l15) * 136 + ks * 32 + 8 * g]);
        const bf16x8 b1f = *reinterpret_cast<const bf16x8*>(&sW1T[(16 + l15) * 136 + ks * 32 + 8 * g]);
        const bf16x8 b2f = *reinterpret_cast<const bf16x8*>(&sW1T[(32 + l15) * 136 + ks * 32 + 8 * g]);
        const bf16x8 b3f = *reinterpret_cast<const bf16x8*>(&sW1T[(48 + l15) * 136 + ks * 32 + 8 * g]);
        acc0  = __builtin_amdgcn_mfma_f32_16x16x32_bf16(afr[ks], b0,  acc0,  0, 0, 0);
        acc1  = __builtin_amdgcn_mfma_f32_16x16x32_bf16(afr[ks], b1f, acc1,  0, 0, 0);
        acc2_ = __builtin_amdgcn_mfma_f32_16x16x32_bf16(afr[ks], b2f, acc2_, 0, 0, 0);
        acc3  = __builtin_amdgcn_mfma_f32_16x16x32_bf16(afr[ks], b3f, acc3,  0, 0, 0);
    }

    {
        const float bb0 = sB1[ 0 + l15], bb1 = sB1[16 + l15];
        const float bb2 = sB1[32 + l15], bb3 = sB1[48 + l15];
        #pragma unroll
        for (int r = 0; r < 4; ++r) {
            const int row = g * 4 + r;
            sH[w][row * 72 +  0 + l15] = f2bf(fmaxf(acc0[r]  + bb0, 0.f));
            sH[w][row * 72 + 16 + l15] = f2bf(fmaxf(acc1[r]  + bb1, 0.f));
            sH[w][row * 72 + 32 + l15] = f2bf(fmaxf(acc2_[r] + bb2, 0.f));
            sH[w][row * 72 + 48 + l15] = f2bf(fmaxf(acc3[r]  + bb3, 0.f));
        }
    }
    __syncthreads();

    bf16x8 a2[2];
    a2[0] = *reinterpret_cast<const bf16x8*>(&sH[w][l15 * 72 +  0 + 8 * g]);
    a2[1] = *reinterpret_cast<const bf16x8*>(&sH[w][l15 * 72 + 32 + 8 * g]);
    f32x4 o[5] = {zero, zero, zero, zero, zero};
    #pragma unroll
    for (int nt = 0; nt < 5; ++nt) {
        #pragma unroll
        for (int ks = 0; ks < 2; ++ks) {
            const bf16x8 bfr = *reinterpret_cast<const bf16x8*>(
                &sW2T[(nt * 16 + l15) * 72 + ks * 32 + 8 * g]);
            o[nt] = __builtin_amdgcn_mfma_f32_16x16x32_bf16(a2[ks], bfr, o[nt], 0, 0, 0);
        }
    }

    #pragma unroll
    for (int nt = 0; nt < 5; ++nt) {
        const int f2 = nt * 16 + l15;
        #pragma unroll
        for (int r = 0; r < 4; ++r) {
            const int node = nbase + g * 4 + r;
            if (node < NN) {
                const float v = o[nt][r];
                if (f2 < 64)   // cols 0..39 = h@W2l, cols 40..63 = 0 padding
                    hW2b[(size_t)node * 64 + f2] = (f2 < 40) ? f2bf(v) : (ushort_t)0;
                if (f2 >= 40)  // feats 40..79 -> base (spans nt = 2, 3, 4)
                    base[(size_t)node * 40 + (f2 - 40)] = v + sB2[f2 - 40];
            }
        }
    }
}

// ---------------------------------------------------------------------------
// K6: gather-mean over hW2b (bf16 stride-64, cols 40..63 zero) + base -> out
// ---------------------------------------------------------------------------
__global__ __launch_bounds__(256, 8) void k_gather2(
    const ushort_t* __restrict__ rows, const int* __restrict__ rowptr,
    const int* __restrict__ srcs, const float* __restrict__ base,
    float* __restrict__ out)
{
    const int lane = threadIdx.x & 63;
    const int w    = threadIdx.x >> 6;
    const int p    = lane & 7;
    const int gb   = lane & 56;
    const int node = blockIdx.x * 32 + w * 8 + (lane >> 3);

    const int beg = rowptr[node];
    const int nb  = rowptr[node + 1] - beg;

    float a0=0,a1=0,a2=0,a3=0,a4=0,a5=0,a6=0,a7=0;
    for (int j0 = 0; j0 < nb; j0 += 8) {
        const int cnt = min(nb - j0, 8);
        const int idx = (p < cnt) ? srcs[beg + j0 + p] : 0;
        int t = 0;
        for (; t + 3 < cnt; t += 4) {
            int s0 = __shfl(idx, gb + t),     s1 = __shfl(idx, gb + t + 1);
            int s2 = __shfl(idx, gb + t + 2), s3 = __shfl(idx, gb + t + 3);
            const uint4 v0 = *reinterpret_cast<const uint4*>(rows + (size_t)s0 * 64 + p * 8);
            const uint4 v1 = *reinterpret_cast<const uint4*>(rows + (size_t)s1 * 64 + p * 8);
            const uint4 v2 = *reinterpret_cast<const uint4*>(rows + (size_t)s2 * 64 + p * 8);
            const uint4 v3 = *reinterpret_cast<const uint4*>(rows + (size_t)s3 * 64 + p * 8);
            a0 += bflo(v0.x)+bflo(v1.x)+bflo(v2.x)+bflo(v3.x);
            a1 += bfhi(v0.x)+bfhi(v1.x)+bfhi(v2.x)+bfhi(v3.x);
            a2 += bflo(v0.y)+bflo(v1.y)+bflo(v2.y)+bflo(v3.y);
            a3 += bfhi(v0.y)+bfhi(v1.y)+bfhi(v2.y)+bfhi(v3.y);
            a4 += bflo(v0.z)+bflo(v1.z)+bflo(v2.z)+bflo(v3.z);
            a5 += bfhi(v0.z)+bfhi(v1.z)+bfhi(v2.z)+bfhi(v3.z);
            a6 += bflo(v0.w)+bflo(v1.w)+bflo(v2.w)+bflo(v3.w);
            a7 += bfhi(v0.w)+bfhi(v1.w)+bfhi(v2.w)+bfhi(v3.w);
        }
        for (; t < cnt; ++t) {
            int s = __shfl(idx, gb + t);
            const uint4 v = *reinterpret_cast<const uint4*>(rows + (size_t)s * 64 + p * 8);
            a0 += bflo(v.x); a1 += bfhi(v.x); a2 += bflo(v.y); a3 += bfhi(v.y);
            a4 += bflo(v.z); a5 += bfhi(v.z); a6 += bflo(v.w); a7 += bfhi(v.w);
        }
    }
    if (p < 5) {
        const float inv = 1.0f / (float)max(nb, 1);
        const float4 bb0 = *reinterpret_cast<const float4*>(base + (size_t)node * 40 + p * 8);
        const float4 bb1 = *reinterpret_cast<const float4*>(base + (size_t)node * 40 + p * 8 + 4);
        float4 r0, r1;
        r0.x = a0*inv + bb0.x; r0.y = a1*inv + bb0.y; r0.z = a2*inv + bb0.z; r0.w = a3*inv + bb0.w;
        r1.x = a4*inv + bb1.x; r1.y = a5*inv + bb1.y; r1.z = a6*inv + bb1.z; r1.w = a7*inv + bb1.w;
        *reinterpret_cast<float4*>(out + (size_t)node * 40 + p * 8)     = r0;
        *reinterpret_cast<float4*>(out + (size_t)node * 40 + p * 8 + 4) = r1;
    }
}

// ---------------------------------------------------------------------------
// Workspace (4-byte units unless noted):
//   [0, NN)            deg_i (int)         <- memset each call
//   [NN, 2NN)          cursor (int)        <- written by scanC
//   [2NN, 3NN+8)       rowptr (int)
//   [3NN+8, +EE)       srcs (int)
//   [.., +NB]          bsum   [.., +NB]  boff
//   then bf16: xb (NN*64), aggm_b (NN*64), hW2b (NN*64); f32: base (NN*40)
// ---------------------------------------------------------------------------
extern "C" void kernel_launch(void* const* d_in, const int* in_sizes, int n_in,
                              void* d_out, int out_size, void* d_ws, size_t ws_size,
                              hipStream_t stream) {
    const float* x   = (const float*)d_in[0];
    const int*   ei  = (const int*)  d_in[1];
    const float* W1l = (const float*)d_in[2];
    const float* W1r = (const float*)d_in[3];
    const float* b1  = (const float*)d_in[4];
    const float* W2l = (const float*)d_in[5];
    const float* W2r = (const float*)d_in[6];
    const float* b2  = (const float*)d_in[7];
    float* out = (float*)d_out;

    int* wsi = (int*)d_ws;
    int* deg_i  = wsi;
    int* cursor = wsi + NN;
    int* rowptr = wsi + 2 * NN;
    int* srcs   = wsi + 3 * NN + 8;
    int* bsum   = srcs + EE;
    int* boff   = bsum + NB;
    ushort_t* xb     = (ushort_t*)(boff + NB + 4);
    ushort_t* aggm_b = xb     + (size_t)NN * 64;
    ushort_t* hW2b   = aggm_b + (size_t)NN * 64;
    float*    base   = (float*)(hW2b + (size_t)NN * 64);

    hipMemsetAsync(deg_i, 0, sizeof(int) * (size_t)NN, stream);

    k_cast<<<NN * 64 / 8 / 256, 256, 0, stream>>>(x, xb);
    k_hist<<<(EE / 4 + 255) / 256, 256, 0, stream>>>(ei, deg_i);
    k_scanA<<<NB, 256, 0, stream>>>(deg_i, bsum);
    k_scanB<<<1, 128, 0, stream>>>(bsum, boff, rowptr);
    k_scanC<<<NB, 256, 0, stream>>>(deg_i, boff, rowptr, cursor);
    k_fill<<<FCH * NXCD, 256, 0, stream>>>(ei, cursor, srcs);
    k_gather1<<<NN / 32, 256, 0, stream>>>(xb, rowptr, srcs, aggm_b);
    k_dense1<<<(NN + 63) / 64, 256, 0, stream>>>(xb, aggm_b, W1l, W1r, b1,
                                                 W2l, W2r, b2, hW2b, base);
    k_gather2<<<NN / 32, 256, 0, stream>>>(hW2b, rowptr, srcs, base, out);
}